// Round 5
// baseline (838.564 us; speedup 1.0000x reference)
//
#include <hip/hip_runtime.h>
#include <hip/hip_bf16.h>
#include <cstdint>
#include <cstddef>

// ---------------------------------------------------------------------------
// Self-attention, B=4 S=2048 D=1024. Inputs FLOAT32, output FLOAT32.
//   Q = x@Wq^T+bq ; K = x@Wk^T+bk ; V = x@Wv^T+bv
//   S = Q@K^T ; P = softmax(S)*(1/32) ; O = P@V
// Compensated bf16 for precision-critical GEMMs: operands as (hi,lo) bf16
// pairs, GEMM K=3072:  A cols [hi|hi|lo] x B cols [hi|lo|hi]
//   => Ahi*Bhi + Ahi*Blo + Alo*Bhi  (near-f32 logits; drops lo*lo ~ 2^-18).
// Round-5 delta vs round 3: OUTPUT IS FLOAT32 (was the whole bug — rounds
// 2-4 produced bit-identical absmax because the pipeline was already right
// and only the final store dtype was wrong).
// Workspace (peak 104 MB):
//   Qp [8192][2048] bf16  @ 0      (32 MB)  hi|lo
//   Kp [8192][2048] bf16  @ 32M    (32 MB)  hi|lo
//   Vt [4][1024][2048]    @ 64M    (16 MB)  V transposed per batch
//   Sc [2048][2048] f32   @ 80M    (16 MB)  per-batch scores (aliases Wp)
//   P  [2048][2048] bf16  @ 96M    ( 8 MB)  per-batch probs
//   Wp 3x[1024][2048] bf16 @ 80M   (12 MB)  dead after qkv (inside Sc)
// ---------------------------------------------------------------------------

typedef __attribute__((ext_vector_type(8))) __bf16 bf16x8;
typedef __attribute__((ext_vector_type(4))) __bf16 bf16x4;
typedef __attribute__((ext_vector_type(4))) float f32x4;

#define BM 128
#define BN 128
#define BK 64

#define NBATCH 4
#define SEQ 2048
#define DIM 1024
#define MTOT (NBATCH * SEQ)   // 8192
#define KTRIP (3 * DIM)       // 3072
#define PAIR (2 * DIM)        // 2048

__device__ __forceinline__ void async_ld16(const void* g, void* l) {
  __builtin_amdgcn_global_load_lds((__attribute__((address_space(1))) void*)(g),
                                   (__attribute__((address_space(3))) void*)(l),
                                   16, 0, 0);
}

struct MapId  { __device__ int operator()(int k) const { return k; } };
struct MapHiA { __device__ int operator()(int k) const { return k < DIM ? k : k - DIM; } };
struct MapHiB { __device__ int operator()(int k) const { return k < PAIR ? k : k - PAIR; } };

// C[m0..+127][n0..+127] += A[m, mapa(k)] * B[n, mapb(k)]  (row-major, B^T GEMM)
// A,B bf16; async global->LDS staging; 4 waves 2x2; 4x4 of 16x16x32 MFMA each.
template <typename MapA, typename MapB>
__device__ __forceinline__ void gemm_core(const __bf16* __restrict__ A, int lda,
                                          const __bf16* __restrict__ B, int ldb,
                                          int K, int m0, int n0,
                                          __bf16* As, __bf16* Bs,
                                          f32x4 (&acc)[4][4],
                                          MapA mapa, MapB mapb) {
  const int t = threadIdx.x;
  const int w = t >> 6;
  const int lrow = t & 15;
  const int quad = (t >> 4) & 3;
  const int wm = (w >> 1) << 6;
  const int wn = (w & 1) << 6;

  const int rb = t >> 3;          // 0..31
  const int co = (t & 7) << 3;    // bf16 col offset 0,8,..,56
  const size_t arow = (size_t)(m0 + rb) * lda + co;
  const size_t brow = (size_t)(n0 + rb) * ldb + co;

  for (int k0 = 0; k0 < K; k0 += BK) {
    const __bf16* Ap = A + arow + mapa(k0);
    const __bf16* Bp = B + brow + mapb(k0);
#pragma unroll
    for (int i = 0; i < 4; ++i)
      async_ld16(Ap + (size_t)(i * 32) * lda, As + i * 2048 + (w << 9));
#pragma unroll
    for (int i = 0; i < 4; ++i)
      async_ld16(Bp + (size_t)(i * 32) * ldb, Bs + i * 2048 + (w << 9));
    __syncthreads();
#pragma unroll
    for (int kk = 0; kk < BK; kk += 32) {
      bf16x8 af[4], bfr[4];
#pragma unroll
      for (int mi = 0; mi < 4; ++mi)
        af[mi] = *(const bf16x8*)(As + (wm + mi * 16 + lrow) * BK + kk + quad * 8);
#pragma unroll
      for (int ni = 0; ni < 4; ++ni)
        bfr[ni] = *(const bf16x8*)(Bs + (wn + ni * 16 + lrow) * BK + kk + quad * 8);
#pragma unroll
      for (int mi = 0; mi < 4; ++mi)
#pragma unroll
        for (int ni = 0; ni < 4; ++ni)
          acc[mi][ni] = __builtin_amdgcn_mfma_f32_16x16x32_bf16(af[mi], bfr[ni],
                                                               acc[mi][ni], 0, 0, 0);
    }
    __syncthreads();
  }
}

// ---------------------------------------------------------------------------
// Kernel 0: f32 [R][1024] -> bf16 [R][2048] as [hi | lo]  (weights only).
__global__ __launch_bounds__(256) void split_kernel(const float* __restrict__ in,
                                                    __bf16* __restrict__ out) {
  const int r = blockIdx.x;
  const int t = threadIdx.x;
  const float4 v = ((const float4*)(in + (size_t)r * DIM))[t];
  __bf16 h0 = (__bf16)v.x, h1 = (__bf16)v.y, h2 = (__bf16)v.z, h3 = (__bf16)v.w;
  bf16x4 hi = {h0, h1, h2, h3};
  bf16x4 lo = {(__bf16)(v.x - (float)h0), (__bf16)(v.y - (float)h1),
               (__bf16)(v.z - (float)h2), (__bf16)(v.w - (float)h3)};
  ((bf16x4*)(out + (size_t)r * PAIR))[t] = hi;
  ((bf16x4*)(out + (size_t)r * PAIR + DIM))[t] = lo;
}

// ---------------------------------------------------------------------------
// Kernel 1: QKV projections. A staged on-the-fly from f32 x (hi/lo per k0
// block); B async from pre-split W pairs. z=0 Qpair, z=1 Kpair, z=2 Vt (K=1024).
__global__ __launch_bounds__(256, 2) void qkv_kernel(
    const float* __restrict__ x,
    const __bf16* __restrict__ Wqp, const float* __restrict__ bq,
    const __bf16* __restrict__ Wkp, const float* __restrict__ bk,
    const __bf16* __restrict__ Wvp, const float* __restrict__ bv,
    __bf16* __restrict__ Qp, __bf16* __restrict__ Kp, __bf16* __restrict__ Vt) {
  __shared__ alignas(16) __bf16 As[BM * BK];
  __shared__ alignas(16) __bf16 Bs[BN * BK];
  f32x4 acc[4][4] = {};
  const int z = blockIdx.z;
  const __bf16* W = (z == 0) ? Wqp : (z == 1) ? Wkp : Wvp;
  const float* bias = (z == 0) ? bq : (z == 1) ? bk : bv;
  const int m0 = blockIdx.y * BM;
  const int n0 = blockIdx.x * BN;
  const int Keff = (z == 2) ? DIM : KTRIP;  // V needs no compensation

  const int t = threadIdx.x;
  const int w = t >> 6;
  const int lrow = t & 15;
  const int quad = (t >> 4) & 3;
  const int wm = (w >> 1) << 6;
  const int wn = (w & 1) << 6;
  const int rb = t >> 3;
  const int co = (t & 7) << 3;

  for (int k0 = 0; k0 < Keff; k0 += BK) {
    // B: async from bf16 pair layout, cols [hi|lo|hi]
    const int kB = (k0 < PAIR) ? k0 : k0 - PAIR;
    const __bf16* Bp = W + (size_t)(n0 + rb) * PAIR + kB + co;
#pragma unroll
    for (int i = 0; i < 4; ++i)
      async_ld16(Bp + (size_t)(i * 32) * PAIR, Bs + i * 2048 + (w << 9));

    // A: from f32 x, plane [hi|hi|lo]
    const int ksrcA = (k0 < DIM) ? k0 : (k0 < PAIR ? k0 - DIM : k0 - PAIR);
    const bool loA = (k0 >= PAIR);
    const float* Asrc = x + (size_t)(m0 + rb) * DIM + ksrcA + co;
#pragma unroll
    for (int i = 0; i < 4; ++i) {
      union { float4 q[2]; float e[8]; } u;
      u.q[0] = *(const float4*)(Asrc + (size_t)(i * 32) * DIM);
      u.q[1] = *(const float4*)(Asrc + (size_t)(i * 32) * DIM + 4);
      union { bf16x8 v; __bf16 e[8]; } o;
#pragma unroll
      for (int j = 0; j < 8; ++j) {
        const float f = u.e[j];
        const __bf16 h = (__bf16)f;
        o.e[j] = loA ? (__bf16)(f - (float)h) : h;
      }
      *(bf16x8*)(As + i * 2048 + t * 8) = o.v;
    }
    __syncthreads();
#pragma unroll
    for (int kk = 0; kk < BK; kk += 32) {
      bf16x8 af[4], bfr[4];
#pragma unroll
      for (int mi = 0; mi < 4; ++mi)
        af[mi] = *(const bf16x8*)(As + (wm + mi * 16 + lrow) * BK + kk + quad * 8);
#pragma unroll
      for (int ni = 0; ni < 4; ++ni)
        bfr[ni] = *(const bf16x8*)(Bs + (wn + ni * 16 + lrow) * BK + kk + quad * 8);
#pragma unroll
      for (int mi = 0; mi < 4; ++mi)
#pragma unroll
        for (int ni = 0; ni < 4; ++ni)
          acc[mi][ni] = __builtin_amdgcn_mfma_f32_16x16x32_bf16(af[mi], bfr[ni],
                                                               acc[mi][ni], 0, 0, 0);
    }
    __syncthreads();
  }

#pragma unroll
  for (int ni = 0; ni < 4; ++ni) {
    const int col = n0 + wn + ni * 16 + lrow;
    const float bb = bias[col];
#pragma unroll
    for (int mi = 0; mi < 4; ++mi) {
#pragma unroll
      for (int r = 0; r < 4; ++r) {
        const int row = m0 + wm + mi * 16 + quad * 4 + r;
        const float v = acc[mi][ni][r] + bb;
        if (z == 2) {
          // Vt[b][col][s]: b = row>>11, s = row&2047
          Vt[(size_t)(((row >> 11) << 10) + col) * SEQ + (row & (SEQ - 1))] = (__bf16)v;
        } else {
          const __bf16 hi = (__bf16)v;
          const __bf16 lo = (__bf16)(v - (float)hi);
          __bf16* base = (z == 0) ? Qp : Kp;
          const size_t off = (size_t)row * PAIR + col;
          base[off] = hi;
          base[off + DIM] = lo;
        }
      }
    }
  }
}

// ---------------------------------------------------------------------------
// Kernel 2: scores = Qb @ Kb^T for ONE batch, compensated (K=3072), f32 out.
__global__ __launch_bounds__(256, 2) void scores_kernel(
    const __bf16* __restrict__ Qb, const __bf16* __restrict__ Kb,
    float* __restrict__ Sc) {
  __shared__ alignas(16) __bf16 As[BM * BK];
  __shared__ alignas(16) __bf16 Bs[BN * BK];
  f32x4 acc[4][4] = {};
  const int m0 = blockIdx.y * BM;
  const int n0 = blockIdx.x * BN;
  gemm_core(Qb, PAIR, Kb, PAIR, KTRIP, m0, n0, As, Bs, acc, MapHiA{}, MapHiB{});
  const int t = threadIdx.x, w = t >> 6, lrow = t & 15, quad = (t >> 4) & 3;
  const int wm = (w >> 1) << 6, wn = (w & 1) << 6;
#pragma unroll
  for (int ni = 0; ni < 4; ++ni) {
    const int col = n0 + wn + ni * 16 + lrow;
#pragma unroll
    for (int mi = 0; mi < 4; ++mi) {
#pragma unroll
      for (int r = 0; r < 4; ++r) {
        const int row = m0 + wm + mi * 16 + quad * 4 + r;
        Sc[(size_t)row * SEQ + col] = acc[mi][ni][r];
      }
    }
  }
}

// ---------------------------------------------------------------------------
// Kernel 3: row softmax for one batch, P = softmax(S)*(1/32), f32 in, bf16 out.
__global__ __launch_bounds__(256) void softmax_kernel(const float* __restrict__ Sc,
                                                      __bf16* __restrict__ P) {
  const int r = blockIdx.x;  // 0..2047
  const float* row = Sc + (size_t)r * SEQ;
  __bf16* prow = P + (size_t)r * SEQ;
  const int t = threadIdx.x;
  const int w = t >> 6;

  const float4 a = ((const float4*)row)[t];
  const float4 c = ((const float4*)row)[t + 256];

  float m = fmaxf(fmaxf(fmaxf(a.x, a.y), fmaxf(a.z, a.w)),
                  fmaxf(fmaxf(c.x, c.y), fmaxf(c.z, c.w)));
#pragma unroll
  for (int o = 32; o; o >>= 1) m = fmaxf(m, __shfl_down(m, o));
  __shared__ float red[8];
  if ((t & 63) == 0) red[w] = m;
  __syncthreads();
  m = fmaxf(fmaxf(red[0], red[1]), fmaxf(red[2], red[3]));

  float e[8];
  e[0] = __expf(a.x - m); e[1] = __expf(a.y - m);
  e[2] = __expf(a.z - m); e[3] = __expf(a.w - m);
  e[4] = __expf(c.x - m); e[5] = __expf(c.y - m);
  e[6] = __expf(c.z - m); e[7] = __expf(c.w - m);
  float s = ((e[0] + e[1]) + (e[2] + e[3])) + ((e[4] + e[5]) + (e[6] + e[7]));
#pragma unroll
  for (int o = 32; o; o >>= 1) s += __shfl_down(s, o);
  if ((t & 63) == 0) red[4 + w] = s;
  __syncthreads();
  s = (red[4] + red[5]) + (red[6] + red[7]);

  const float sc = 0.03125f / s;  // post-softmax 1/sqrt(Dk)=1/32 folded in
  bf16x4 o1 = {(__bf16)(e[0] * sc), (__bf16)(e[1] * sc),
               (__bf16)(e[2] * sc), (__bf16)(e[3] * sc)};
  bf16x4 o2 = {(__bf16)(e[4] * sc), (__bf16)(e[5] * sc),
               (__bf16)(e[6] * sc), (__bf16)(e[7] * sc)};
  ((bf16x4*)prow)[t] = o1;
  ((bf16x4*)prow)[t + 256] = o2;
}

// ---------------------------------------------------------------------------
// Kernel 4: Ob = P @ Vb for one batch (Vtb is [v][s] -> B^T GEMM, K=2048).
// FLOAT32 output.
__global__ __launch_bounds__(256, 2) void pv_kernel(
    const __bf16* __restrict__ P, const __bf16* __restrict__ Vtb,
    float* __restrict__ ob) {
  __shared__ alignas(16) __bf16 As[BM * BK];
  __shared__ alignas(16) __bf16 Bs[BN * BK];
  f32x4 acc[4][4] = {};
  const int m0 = blockIdx.y * BM;
  const int n0 = blockIdx.x * BN;
  gemm_core(P, SEQ, Vtb, SEQ, SEQ, m0, n0, As, Bs, acc, MapId{}, MapId{});
  const int t = threadIdx.x, w = t >> 6, lrow = t & 15, quad = (t >> 4) & 3;
  const int wm = (w >> 1) << 6, wn = (w & 1) << 6;
#pragma unroll
  for (int ni = 0; ni < 4; ++ni) {
    const int col = n0 + wn + ni * 16 + lrow;
#pragma unroll
    for (int mi = 0; mi < 4; ++mi) {
#pragma unroll
      for (int r = 0; r < 4; ++r) {
        const int row = m0 + wm + mi * 16 + quad * 4 + r;
        ob[(size_t)row * DIM + col] = acc[mi][ni][r];
      }
    }
  }
}

// ---------------------------------------------------------------------------
extern "C" void kernel_launch(void* const* d_in, const int* in_sizes, int n_in,
                              void* d_out, int out_size, void* d_ws, size_t ws_size,
                              hipStream_t stream) {
  const float* x  = (const float*)d_in[0];
  const float* Wq = (const float*)d_in[1];
  const float* bq = (const float*)d_in[2];
  const float* Wk = (const float*)d_in[3];
  const float* bk = (const float*)d_in[4];
  const float* Wv = (const float*)d_in[5];
  const float* bv = (const float*)d_in[6];
  float* out = (float*)d_out;  // reference output dtype is float32

  char* ws = (char*)d_ws;
  __bf16* Qp  = (__bf16*)(ws);                 // 33,554,432 B
  __bf16* Kp  = (__bf16*)(ws + 33554432);      // 33,554,432 B
  __bf16* Vt  = (__bf16*)(ws + 67108864);      // 16,777,216 B
  float*  Sc  = (float*)(ws + 83886080);       // 16,777,216 B (per batch)
  __bf16* P   = (__bf16*)(ws + 100663296);     //  8,388,608 B (per batch)
  // W pairs alias the Sc region (dead once scores_kernel first runs):
  __bf16* Wqp = (__bf16*)(ws + 83886080);      //  4,194,304 B
  __bf16* Wkp = (__bf16*)(ws + 88080384);      //  4,194,304 B
  __bf16* Wvp = (__bf16*)(ws + 92274688);      //  4,194,304 B
  // peak usage: 109,051,904 B (104 MB)

  dim3 blk(256, 1, 1);
  split_kernel<<<dim3(DIM), blk, 0, stream>>>(Wq, Wqp);
  split_kernel<<<dim3(DIM), blk, 0, stream>>>(Wk, Wkp);
  split_kernel<<<dim3(DIM), blk, 0, stream>>>(Wv, Wvp);
  qkv_kernel<<<dim3(DIM / BN, MTOT / BM, 3), blk, 0, stream>>>(
      x, Wqp, bq, Wkp, bk, Wvp, bv, Qp, Kp, Vt);
  for (int b = 0; b < NBATCH; ++b) {
    scores_kernel<<<dim3(SEQ / BN, SEQ / BM, 1), blk, 0, stream>>>(
        Qp + (size_t)b * SEQ * PAIR, Kp + (size_t)b * SEQ * PAIR, Sc);
    softmax_kernel<<<dim3(SEQ), blk, 0, stream>>>(Sc, P);
    pv_kernel<<<dim3(DIM / BN, SEQ / BM, 1), blk, 0, stream>>>(
        P, Vt + (size_t)b * DIM * SEQ, out + (size_t)b * SEQ * DIM);
  }
}

// Round 6
// 452.561 us; speedup vs baseline: 1.8529x; 1.8529x over previous
//
#include <hip/hip_runtime.h>
#include <hip/hip_bf16.h>
#include <cstdint>
#include <cstddef>

// ---------------------------------------------------------------------------
// Self-attention, B=4 S=2048 D=1024. Inputs FLOAT32, output FLOAT32.
//   Q = x@Wq^T+bq ; K = x@Wk^T+bk ; V = x@Wv^T+bv
//   S = Q@K^T ; P = softmax(S)*(1/32) ; O = P@V
// Compensated bf16 GEMMs: operands as (hi,lo) bf16 pairs, K=3072 with
//   A cols [hi|hi|lo] x B cols [hi|lo|hi] => AhiBhi + AhiBlo + AloBhi.
// Round-6 deltas vs round 5 (838 us):
//   * x pre-split to bf16 pairs once -> qkv is a pure dual-async m97 GEMM
//     (round 5 qkv burned 32% VALUBusy on per-tile f32->hi/lo conversion,
//     re-done 24x per x element; MfmaUtil was 16.6%).
//   * scores/softmax/pv batched over blockIdx.z (one launch each; round 5
//     ran 4 serial launches, pv grid=128 blocks left half the CUs idle).
// Workspace (peak 184,549,376 B — round 2 proved this size works):
//   Qp [8192][2048] bf16 @ 0      (32 MB)  hi|lo
//   Kp [8192][2048] bf16 @ 32M    (32 MB)  hi|lo
//   Vt [4][1024][2048]   @ 64M    (16 MB)  V transposed per batch
//   Sc [4][2048][2048]f32@ 80M    (64 MB)  scores
//   P  [4][2048][2048]   @ 144M   (32 MB)  probs bf16
//   xp [8192][2048] bf16 @ 80M    (32 MB)  aliases Sc (dead after qkv)
//   Wp 3x[1024][2048]    @ 112M   (12 MB)  aliases Sc (dead after qkv)
// ---------------------------------------------------------------------------

typedef __attribute__((ext_vector_type(8))) __bf16 bf16x8;
typedef __attribute__((ext_vector_type(4))) __bf16 bf16x4;
typedef __attribute__((ext_vector_type(4))) float f32x4;

#define BM 128
#define BN 128
#define BK 64

#define NBATCH 4
#define SEQ 2048
#define DIM 1024
#define MTOT (NBATCH * SEQ)   // 8192
#define KTRIP (3 * DIM)       // 3072
#define PAIR (2 * DIM)        // 2048

__device__ __forceinline__ void async_ld16(const void* g, void* l) {
  __builtin_amdgcn_global_load_lds((__attribute__((address_space(1))) void*)(g),
                                   (__attribute__((address_space(3))) void*)(l),
                                   16, 0, 0);
}

struct MapId  { __device__ int operator()(int k) const { return k; } };
struct MapHiA { __device__ int operator()(int k) const { return k < DIM ? k : k - DIM; } };
struct MapHiB { __device__ int operator()(int k) const { return k < PAIR ? k : k - PAIR; } };

// C[m0..+127][n0..+127] += A[m, mapa(k)] * B[n, mapb(k)]  (row-major, B^T GEMM)
// A,B bf16; async global->LDS staging; 4 waves 2x2; 4x4 of 16x16x32 MFMA each.
template <typename MapA, typename MapB>
__device__ __forceinline__ void gemm_core(const __bf16* __restrict__ A, int lda,
                                          const __bf16* __restrict__ B, int ldb,
                                          int K, int m0, int n0,
                                          __bf16* As, __bf16* Bs,
                                          f32x4 (&acc)[4][4],
                                          MapA mapa, MapB mapb) {
  const int t = threadIdx.x;
  const int w = t >> 6;
  const int lrow = t & 15;
  const int quad = (t >> 4) & 3;
  const int wm = (w >> 1) << 6;
  const int wn = (w & 1) << 6;

  const int rb = t >> 3;          // 0..31
  const int co = (t & 7) << 3;    // bf16 col offset 0,8,..,56
  const size_t arow = (size_t)(m0 + rb) * lda + co;
  const size_t brow = (size_t)(n0 + rb) * ldb + co;

  for (int k0 = 0; k0 < K; k0 += BK) {
    const __bf16* Ap = A + arow + mapa(k0);
    const __bf16* Bp = B + brow + mapb(k0);
#pragma unroll
    for (int i = 0; i < 4; ++i)
      async_ld16(Ap + (size_t)(i * 32) * lda, As + i * 2048 + (w << 9));
#pragma unroll
    for (int i = 0; i < 4; ++i)
      async_ld16(Bp + (size_t)(i * 32) * ldb, Bs + i * 2048 + (w << 9));
    __syncthreads();
#pragma unroll
    for (int kk = 0; kk < BK; kk += 32) {
      bf16x8 af[4], bfr[4];
#pragma unroll
      for (int mi = 0; mi < 4; ++mi)
        af[mi] = *(const bf16x8*)(As + (wm + mi * 16 + lrow) * BK + kk + quad * 8);
#pragma unroll
      for (int ni = 0; ni < 4; ++ni)
        bfr[ni] = *(const bf16x8*)(Bs + (wn + ni * 16 + lrow) * BK + kk + quad * 8);
#pragma unroll
      for (int mi = 0; mi < 4; ++mi)
#pragma unroll
        for (int ni = 0; ni < 4; ++ni)
          acc[mi][ni] = __builtin_amdgcn_mfma_f32_16x16x32_bf16(af[mi], bfr[ni],
                                                               acc[mi][ni], 0, 0, 0);
    }
    __syncthreads();
  }
}

// ---------------------------------------------------------------------------
// Kernel 0: f32 [R][1024] -> bf16 [R][2048] as [hi | lo].
__global__ __launch_bounds__(256) void split_kernel(const float* __restrict__ in,
                                                    __bf16* __restrict__ out) {
  const int r = blockIdx.x;
  const int t = threadIdx.x;
  const float4 v = ((const float4*)(in + (size_t)r * DIM))[t];
  __bf16 h0 = (__bf16)v.x, h1 = (__bf16)v.y, h2 = (__bf16)v.z, h3 = (__bf16)v.w;
  bf16x4 hi = {h0, h1, h2, h3};
  bf16x4 lo = {(__bf16)(v.x - (float)h0), (__bf16)(v.y - (float)h1),
               (__bf16)(v.z - (float)h2), (__bf16)(v.w - (float)h3)};
  ((bf16x4*)(out + (size_t)r * PAIR))[t] = hi;
  ((bf16x4*)(out + (size_t)r * PAIR + DIM))[t] = lo;
}

// ---------------------------------------------------------------------------
// Kernel 1: QKV projections from pre-split pairs. z=0 Qp, z=1 Kp, z=2 Vt(K=1024).
__global__ __launch_bounds__(256, 2) void qkv_kernel(
    const __bf16* __restrict__ xp,
    const __bf16* __restrict__ Wqp, const float* __restrict__ bq,
    const __bf16* __restrict__ Wkp, const float* __restrict__ bk,
    const __bf16* __restrict__ Wvp, const float* __restrict__ bv,
    __bf16* __restrict__ Qp, __bf16* __restrict__ Kp, __bf16* __restrict__ Vt) {
  __shared__ alignas(16) __bf16 As[BM * BK];
  __shared__ alignas(16) __bf16 Bs[BN * BK];
  f32x4 acc[4][4] = {};
  const int z = blockIdx.z;
  const __bf16* W = (z == 0) ? Wqp : (z == 1) ? Wkp : Wvp;
  const float* bias = (z == 0) ? bq : (z == 1) ? bk : bv;
  const int m0 = blockIdx.y * BM;
  const int n0 = blockIdx.x * BN;
  const int Keff = (z == 2) ? DIM : KTRIP;  // V needs no compensation
  gemm_core(xp, PAIR, W, PAIR, Keff, m0, n0, As, Bs, acc, MapHiA{}, MapHiB{});

  const int t = threadIdx.x, w = t >> 6, lrow = t & 15, quad = (t >> 4) & 3;
  const int wm = (w >> 1) << 6, wn = (w & 1) << 6;
#pragma unroll
  for (int ni = 0; ni < 4; ++ni) {
    const int col = n0 + wn + ni * 16 + lrow;
    const float bb = bias[col];
#pragma unroll
    for (int mi = 0; mi < 4; ++mi) {
#pragma unroll
      for (int r = 0; r < 4; ++r) {
        const int row = m0 + wm + mi * 16 + quad * 4 + r;
        const float v = acc[mi][ni][r] + bb;
        if (z == 2) {
          // Vt[b][col][s]: b = row>>11, s = row&2047
          Vt[(size_t)(((row >> 11) << 10) + col) * SEQ + (row & (SEQ - 1))] = (__bf16)v;
        } else {
          const __bf16 hi = (__bf16)v;
          const __bf16 lo = (__bf16)(v - (float)hi);
          __bf16* base = (z == 0) ? Qp : Kp;
          const size_t off = (size_t)row * PAIR + col;
          base[off] = hi;
          base[off + DIM] = lo;
        }
      }
    }
  }
}

// ---------------------------------------------------------------------------
// Kernel 2: scores[b] = Q[b] @ K[b]^T, compensated (K=3072), f32 out. z=batch.
__global__ __launch_bounds__(256, 2) void scores_kernel(
    const __bf16* __restrict__ Qp, const __bf16* __restrict__ Kp,
    float* __restrict__ Sc) {
  __shared__ alignas(16) __bf16 As[BM * BK];
  __shared__ alignas(16) __bf16 Bs[BN * BK];
  f32x4 acc[4][4] = {};
  const int b = blockIdx.z;
  const int m0 = blockIdx.y * BM;
  const int n0 = blockIdx.x * BN;
  gemm_core(Qp + (size_t)b * SEQ * PAIR, PAIR,
            Kp + (size_t)b * SEQ * PAIR, PAIR, KTRIP, m0, n0, As, Bs, acc,
            MapHiA{}, MapHiB{});
  float* out = Sc + (size_t)b * SEQ * SEQ;
  const int t = threadIdx.x, w = t >> 6, lrow = t & 15, quad = (t >> 4) & 3;
  const int wm = (w >> 1) << 6, wn = (w & 1) << 6;
#pragma unroll
  for (int ni = 0; ni < 4; ++ni) {
    const int col = n0 + wn + ni * 16 + lrow;
#pragma unroll
    for (int mi = 0; mi < 4; ++mi) {
#pragma unroll
      for (int r = 0; r < 4; ++r) {
        const int row = m0 + wm + mi * 16 + quad * 4 + r;
        out[(size_t)row * SEQ + col] = acc[mi][ni][r];
      }
    }
  }
}

// ---------------------------------------------------------------------------
// Kernel 3: row softmax over all batches, P = softmax(S)*(1/32), bf16 out.
__global__ __launch_bounds__(256) void softmax_kernel(const float* __restrict__ Sc,
                                                      __bf16* __restrict__ P) {
  const int r = blockIdx.x;  // 0..8191 (batch-contiguous rows)
  const float* row = Sc + (size_t)r * SEQ;
  __bf16* prow = P + (size_t)r * SEQ;
  const int t = threadIdx.x;
  const int w = t >> 6;

  const float4 a = ((const float4*)row)[t];
  const float4 c = ((const float4*)row)[t + 256];

  float m = fmaxf(fmaxf(fmaxf(a.x, a.y), fmaxf(a.z, a.w)),
                  fmaxf(fmaxf(c.x, c.y), fmaxf(c.z, c.w)));
#pragma unroll
  for (int o = 32; o; o >>= 1) m = fmaxf(m, __shfl_down(m, o));
  __shared__ float red[8];
  if ((t & 63) == 0) red[w] = m;
  __syncthreads();
  m = fmaxf(fmaxf(red[0], red[1]), fmaxf(red[2], red[3]));

  float e[8];
  e[0] = __expf(a.x - m); e[1] = __expf(a.y - m);
  e[2] = __expf(a.z - m); e[3] = __expf(a.w - m);
  e[4] = __expf(c.x - m); e[5] = __expf(c.y - m);
  e[6] = __expf(c.z - m); e[7] = __expf(c.w - m);
  float s = ((e[0] + e[1]) + (e[2] + e[3])) + ((e[4] + e[5]) + (e[6] + e[7]));
#pragma unroll
  for (int o = 32; o; o >>= 1) s += __shfl_down(s, o);
  if ((t & 63) == 0) red[4 + w] = s;
  __syncthreads();
  s = (red[4] + red[5]) + (red[6] + red[7]);

  const float sc = 0.03125f / s;  // post-softmax 1/sqrt(Dk)=1/32 folded in
  bf16x4 o1 = {(__bf16)(e[0] * sc), (__bf16)(e[1] * sc),
               (__bf16)(e[2] * sc), (__bf16)(e[3] * sc)};
  bf16x4 o2 = {(__bf16)(e[4] * sc), (__bf16)(e[5] * sc),
               (__bf16)(e[6] * sc), (__bf16)(e[7] * sc)};
  ((bf16x4*)prow)[t] = o1;
  ((bf16x4*)prow)[t + 256] = o2;
}

// ---------------------------------------------------------------------------
// Kernel 4: O[b] = P[b] @ V[b]  (Vt [v][s] -> B^T GEMM, K=2048), f32 out. z=batch.
__global__ __launch_bounds__(256, 2) void pv_kernel(
    const __bf16* __restrict__ P, const __bf16* __restrict__ Vt,
    float* __restrict__ out) {
  __shared__ alignas(16) __bf16 As[BM * BK];
  __shared__ alignas(16) __bf16 Bs[BN * BK];
  f32x4 acc[4][4] = {};
  const int b = blockIdx.z;
  const int m0 = blockIdx.y * BM;
  const int n0 = blockIdx.x * BN;
  gemm_core(P + (size_t)b * SEQ * SEQ, SEQ,
            Vt + (size_t)b * DIM * SEQ, SEQ, SEQ, m0, n0, As, Bs, acc,
            MapId{}, MapId{});
  float* ob = out + (size_t)b * SEQ * DIM;
  const int t = threadIdx.x, w = t >> 6, lrow = t & 15, quad = (t >> 4) & 3;
  const int wm = (w >> 1) << 6, wn = (w & 1) << 6;
#pragma unroll
  for (int ni = 0; ni < 4; ++ni) {
    const int col = n0 + wn + ni * 16 + lrow;
#pragma unroll
    for (int mi = 0; mi < 4; ++mi) {
#pragma unroll
      for (int r = 0; r < 4; ++r) {
        const int row = m0 + wm + mi * 16 + quad * 4 + r;
        ob[(size_t)row * DIM + col] = acc[mi][ni][r];
      }
    }
  }
}

// ---------------------------------------------------------------------------
extern "C" void kernel_launch(void* const* d_in, const int* in_sizes, int n_in,
                              void* d_out, int out_size, void* d_ws, size_t ws_size,
                              hipStream_t stream) {
  const float* x  = (const float*)d_in[0];
  const float* Wq = (const float*)d_in[1];
  const float* bq = (const float*)d_in[2];
  const float* Wk = (const float*)d_in[3];
  const float* bk = (const float*)d_in[4];
  const float* Wv = (const float*)d_in[5];
  const float* bv = (const float*)d_in[6];
  float* out = (float*)d_out;  // reference output dtype is float32

  char* ws = (char*)d_ws;
  __bf16* Qp  = (__bf16*)(ws);                 // 32 MB
  __bf16* Kp  = (__bf16*)(ws + 33554432);      // 32 MB
  __bf16* Vt  = (__bf16*)(ws + 67108864);      // 16 MB
  float*  Sc  = (float*)(ws + 83886080);       // 64 MB [4][2048][2048] f32
  __bf16* P   = (__bf16*)(ws + 150994944);     // 32 MB [4][2048][2048] bf16
  // xp + W pairs alias the Sc region (dead once scores_kernel runs):
  __bf16* xp  = (__bf16*)(ws + 83886080);      // 32 MB
  __bf16* Wqp = (__bf16*)(ws + 117440512);     //  4 MB
  __bf16* Wkp = (__bf16*)(ws + 121634816);     //  4 MB
  __bf16* Wvp = (__bf16*)(ws + 125829120);     //  4 MB
  // peak 184,549,376 B

  dim3 blk(256, 1, 1);
  split_kernel<<<dim3(MTOT), blk, 0, stream>>>(x, xp);
  split_kernel<<<dim3(DIM), blk, 0, stream>>>(Wq, Wqp);
  split_kernel<<<dim3(DIM), blk, 0, stream>>>(Wk, Wkp);
  split_kernel<<<dim3(DIM), blk, 0, stream>>>(Wv, Wvp);
  qkv_kernel<<<dim3(DIM / BN, MTOT / BM, 3), blk, 0, stream>>>(
      xp, Wqp, bq, Wkp, bk, Wvp, bv, Qp, Kp, Vt);
  scores_kernel<<<dim3(SEQ / BN, SEQ / BM, NBATCH), blk, 0, stream>>>(Qp, Kp, Sc);
  softmax_kernel<<<dim3(MTOT), blk, 0, stream>>>(Sc, P);
  pv_kernel<<<dim3(DIM / BN, SEQ / BM, NBATCH), blk, 0, stream>>>(P, Vt, out);
}

// Round 7
// 422.750 us; speedup vs baseline: 1.9836x; 1.0705x over previous
//
#include <hip/hip_runtime.h>
#include <hip/hip_bf16.h>
#include <cstdint>
#include <cstddef>

// ---------------------------------------------------------------------------
// Self-attention, B=4 S=2048 D=1024. Inputs FLOAT32, output FLOAT32.
//   Q = x@Wq^T+bq ; K = x@Wk^T+bk ; V = x@Wv^T+bv
//   S = Q@K^T ; P = softmax(S)*(1/32) ; O = P@V
// Compensated bf16 GEMMs: operands as (hi,lo) bf16 pairs, K=3072 with
//   A cols [hi|hi|lo] x B cols [hi|lo|hi] => AhiBhi + AhiBlo + AloBhi.
// Round-7 delta vs round 6 (452 us): XOR-swizzled LDS tile layout.
//   Old layout: 64-col rows = 128 B = exactly 32 banks -> every fragment
//   ds_read_b128 hit one 4-bank group with 16 lanes (SQ_LDS_BANK_CONFLICT
//   4.4e7/dispatch). New: lane staging (row lr, slot s) fetches global
//   colblock s^(lr&7) (global side of global_load_lds is per-lane, LDS dest
//   stays base+16*lane contiguous); fragment reads use slot cb^(lr&7).
//   A wave's b128 now spreads 2 lanes/bank-group over all 32 banks (2-way
//   aliasing is free, m136).
// Workspace (peak 184,549,376 B):
//   Qp [8192][2048] bf16 @ 0      (32 MB)  hi|lo
//   Kp [8192][2048] bf16 @ 32M    (32 MB)  hi|lo
//   Vt [4][1024][2048]   @ 64M    (16 MB)  V transposed per batch
//   Sc [4][2048][2048]f32@ 80M    (64 MB)  scores
//   P  [4][2048][2048]   @ 144M   (32 MB)  probs bf16
//   xp [8192][2048] bf16 @ 80M    (32 MB)  aliases Sc (dead after qkv)
//   Wp 3x[1024][2048]    @ 112M   (12 MB)  aliases Sc (dead after qkv)
// ---------------------------------------------------------------------------

typedef __attribute__((ext_vector_type(8))) __bf16 bf16x8;
typedef __attribute__((ext_vector_type(4))) __bf16 bf16x4;
typedef __attribute__((ext_vector_type(4))) float f32x4;

#define BM 128
#define BN 128
#define BK 64

#define NBATCH 4
#define SEQ 2048
#define DIM 1024
#define MTOT (NBATCH * SEQ)   // 8192
#define KTRIP (3 * DIM)       // 3072
#define PAIR (2 * DIM)        // 2048

__device__ __forceinline__ void async_ld16(const void* g, void* l) {
  __builtin_amdgcn_global_load_lds((__attribute__((address_space(1))) void*)(g),
                                   (__attribute__((address_space(3))) void*)(l),
                                   16, 0, 0);
}

struct MapId  { __device__ int operator()(int k) const { return k; } };
struct MapHiA { __device__ int operator()(int k) const { return k < DIM ? k : k - DIM; } };
struct MapHiB { __device__ int operator()(int k) const { return k < PAIR ? k : k - PAIR; } };

// C[m0..+127][n0..+127] += A[m, mapa(k)] * B[n, mapb(k)]  (row-major, B^T GEMM)
// A,B bf16; async global->LDS staging (XOR-swizzled slots); 4 waves 2x2;
// each wave 64x64 via 4x4 of 16x16x32 bf16 MFMA.
template <typename MapA, typename MapB>
__device__ __forceinline__ void gemm_core(const __bf16* __restrict__ A, int lda,
                                          const __bf16* __restrict__ B, int ldb,
                                          int K, int m0, int n0,
                                          __bf16* As, __bf16* Bs,
                                          f32x4 (&acc)[4][4],
                                          MapA mapa, MapB mapb) {
  const int t = threadIdx.x;
  const int w = t >> 6;
  const int lrow = t & 15;
  const int quad = (t >> 4) & 3;
  const int wm = (w >> 1) << 6;
  const int wn = (w & 1) << 6;

  // Staging: thread t covers tile row rb (+32 per i), global colblock
  // (t&7)^(rb&7) (XOR swizzle; LDS dest is the wave-contiguous slot t&7).
  const int rb = t >> 3;                               // 0..31
  const int co = (((t & 7) ^ (rb & 7)) << 3);          // swizzled source col
  const size_t arow = (size_t)(m0 + rb) * lda + co;
  const size_t brow = (size_t)(n0 + rb) * ldb + co;

  const int sw = lrow & 7;  // row-phase for read-side swizzle

  for (int k0 = 0; k0 < K; k0 += BK) {
    const __bf16* Ap = A + arow + mapa(k0);
    const __bf16* Bp = B + brow + mapb(k0);
#pragma unroll
    for (int i = 0; i < 4; ++i)
      async_ld16(Ap + (size_t)(i * 32) * lda, As + i * 2048 + (w << 9));
#pragma unroll
    for (int i = 0; i < 4; ++i)
      async_ld16(Bp + (size_t)(i * 32) * ldb, Bs + i * 2048 + (w << 9));
    __syncthreads();
#pragma unroll
    for (int kk = 0; kk < BK; kk += 32) {
      const int slot = ((kk >> 3) + quad) ^ sw;  // swizzled 8-elt slot index
      bf16x8 af[4], bfr[4];
#pragma unroll
      for (int mi = 0; mi < 4; ++mi)
        af[mi] = *(const bf16x8*)(As + (wm + mi * 16 + lrow) * BK + (slot << 3));
#pragma unroll
      for (int ni = 0; ni < 4; ++ni)
        bfr[ni] = *(const bf16x8*)(Bs + (wn + ni * 16 + lrow) * BK + (slot << 3));
#pragma unroll
      for (int mi = 0; mi < 4; ++mi)
#pragma unroll
        for (int ni = 0; ni < 4; ++ni)
          acc[mi][ni] = __builtin_amdgcn_mfma_f32_16x16x32_bf16(af[mi], bfr[ni],
                                                               acc[mi][ni], 0, 0, 0);
    }
    __syncthreads();
  }
}

// ---------------------------------------------------------------------------
// Kernel 0: f32 [R][1024] -> bf16 [R][2048] as [hi | lo].
__global__ __launch_bounds__(256) void split_kernel(const float* __restrict__ in,
                                                    __bf16* __restrict__ out) {
  const int r = blockIdx.x;
  const int t = threadIdx.x;
  const float4 v = ((const float4*)(in + (size_t)r * DIM))[t];
  __bf16 h0 = (__bf16)v.x, h1 = (__bf16)v.y, h2 = (__bf16)v.z, h3 = (__bf16)v.w;
  bf16x4 hi = {h0, h1, h2, h3};
  bf16x4 lo = {(__bf16)(v.x - (float)h0), (__bf16)(v.y - (float)h1),
               (__bf16)(v.z - (float)h2), (__bf16)(v.w - (float)h3)};
  ((bf16x4*)(out + (size_t)r * PAIR))[t] = hi;
  ((bf16x4*)(out + (size_t)r * PAIR + DIM))[t] = lo;
}

// ---------------------------------------------------------------------------
// Kernel 1: QKV projections from pre-split pairs. z=0 Qp, z=1 Kp, z=2 Vt(K=1024).
__global__ __launch_bounds__(256, 2) void qkv_kernel(
    const __bf16* __restrict__ xp,
    const __bf16* __restrict__ Wqp, const float* __restrict__ bq,
    const __bf16* __restrict__ Wkp, const float* __restrict__ bk,
    const __bf16* __restrict__ Wvp, const float* __restrict__ bv,
    __bf16* __restrict__ Qp, __bf16* __restrict__ Kp, __bf16* __restrict__ Vt) {
  __shared__ alignas(16) __bf16 As[BM * BK];
  __shared__ alignas(16) __bf16 Bs[BN * BK];
  f32x4 acc[4][4] = {};
  const int z = blockIdx.z;
  const __bf16* W = (z == 0) ? Wqp : (z == 1) ? Wkp : Wvp;
  const float* bias = (z == 0) ? bq : (z == 1) ? bk : bv;
  const int m0 = blockIdx.y * BM;
  const int n0 = blockIdx.x * BN;
  const int Keff = (z == 2) ? DIM : KTRIP;  // V needs no compensation
  gemm_core(xp, PAIR, W, PAIR, Keff, m0, n0, As, Bs, acc, MapHiA{}, MapHiB{});

  const int t = threadIdx.x, w = t >> 6, lrow = t & 15, quad = (t >> 4) & 3;
  const int wm = (w >> 1) << 6, wn = (w & 1) << 6;
#pragma unroll
  for (int ni = 0; ni < 4; ++ni) {
    const int col = n0 + wn + ni * 16 + lrow;
    const float bb = bias[col];
#pragma unroll
    for (int mi = 0; mi < 4; ++mi) {
#pragma unroll
      for (int r = 0; r < 4; ++r) {
        const int row = m0 + wm + mi * 16 + quad * 4 + r;
        const float v = acc[mi][ni][r] + bb;
        if (z == 2) {
          // Vt[b][col][s]: b = row>>11, s = row&2047
          Vt[(size_t)(((row >> 11) << 10) + col) * SEQ + (row & (SEQ - 1))] = (__bf16)v;
        } else {
          const __bf16 hi = (__bf16)v;
          const __bf16 lo = (__bf16)(v - (float)hi);
          __bf16* base = (z == 0) ? Qp : Kp;
          const size_t off = (size_t)row * PAIR + col;
          base[off] = hi;
          base[off + DIM] = lo;
        }
      }
    }
  }
}

// ---------------------------------------------------------------------------
// Kernel 2: scores[b] = Q[b] @ K[b]^T, compensated (K=3072), f32 out. z=batch.
__global__ __launch_bounds__(256, 2) void scores_kernel(
    const __bf16* __restrict__ Qp, const __bf16* __restrict__ Kp,
    float* __restrict__ Sc) {
  __shared__ alignas(16) __bf16 As[BM * BK];
  __shared__ alignas(16) __bf16 Bs[BN * BK];
  f32x4 acc[4][4] = {};
  const int b = blockIdx.z;
  const int m0 = blockIdx.y * BM;
  const int n0 = blockIdx.x * BN;
  gemm_core(Qp + (size_t)b * SEQ * PAIR, PAIR,
            Kp + (size_t)b * SEQ * PAIR, PAIR, KTRIP, m0, n0, As, Bs, acc,
            MapHiA{}, MapHiB{});
  float* out = Sc + (size_t)b * SEQ * SEQ;
  const int t = threadIdx.x, w = t >> 6, lrow = t & 15, quad = (t >> 4) & 3;
  const int wm = (w >> 1) << 6, wn = (w & 1) << 6;
#pragma unroll
  for (int ni = 0; ni < 4; ++ni) {
    const int col = n0 + wn + ni * 16 + lrow;
#pragma unroll
    for (int mi = 0; mi < 4; ++mi) {
#pragma unroll
      for (int r = 0; r < 4; ++r) {
        const int row = m0 + wm + mi * 16 + quad * 4 + r;
        out[(size_t)row * SEQ + col] = acc[mi][ni][r];
      }
    }
  }
}

// ---------------------------------------------------------------------------
// Kernel 3: row softmax over all batches, P = softmax(S)*(1/32), bf16 out.
__global__ __launch_bounds__(256) void softmax_kernel(const float* __restrict__ Sc,
                                                      __bf16* __restrict__ P) {
  const int r = blockIdx.x;  // 0..8191 (batch-contiguous rows)
  const float* row = Sc + (size_t)r * SEQ;
  __bf16* prow = P + (size_t)r * SEQ;
  const int t = threadIdx.x;
  const int w = t >> 6;

  const float4 a = ((const float4*)row)[t];
  const float4 c = ((const float4*)row)[t + 256];

  float m = fmaxf(fmaxf(fmaxf(a.x, a.y), fmaxf(a.z, a.w)),
                  fmaxf(fmaxf(c.x, c.y), fmaxf(c.z, c.w)));
#pragma unroll
  for (int o = 32; o; o >>= 1) m = fmaxf(m, __shfl_down(m, o));
  __shared__ float red[8];
  if ((t & 63) == 0) red[w] = m;
  __syncthreads();
  m = fmaxf(fmaxf(red[0], red[1]), fmaxf(red[2], red[3]));

  float e[8];
  e[0] = __expf(a.x - m); e[1] = __expf(a.y - m);
  e[2] = __expf(a.z - m); e[3] = __expf(a.w - m);
  e[4] = __expf(c.x - m); e[5] = __expf(c.y - m);
  e[6] = __expf(c.z - m); e[7] = __expf(c.w - m);
  float s = ((e[0] + e[1]) + (e[2] + e[3])) + ((e[4] + e[5]) + (e[6] + e[7]));
#pragma unroll
  for (int o = 32; o; o >>= 1) s += __shfl_down(s, o);
  if ((t & 63) == 0) red[4 + w] = s;
  __syncthreads();
  s = (red[4] + red[5]) + (red[6] + red[7]);

  const float sc = 0.03125f / s;  // post-softmax 1/sqrt(Dk)=1/32 folded in
  bf16x4 o1 = {(__bf16)(e[0] * sc), (__bf16)(e[1] * sc),
               (__bf16)(e[2] * sc), (__bf16)(e[3] * sc)};
  bf16x4 o2 = {(__bf16)(e[4] * sc), (__bf16)(e[5] * sc),
               (__bf16)(e[6] * sc), (__bf16)(e[7] * sc)};
  ((bf16x4*)prow)[t] = o1;
  ((bf16x4*)prow)[t + 256] = o2;
}

// ---------------------------------------------------------------------------
// Kernel 4: O[b] = P[b] @ V[b]  (Vt [v][s] -> B^T GEMM, K=2048), f32 out. z=batch.
__global__ __launch_bounds__(256, 2) void pv_kernel(
    const __bf16* __restrict__ P, const __bf16* __restrict__ Vt,
    float* __restrict__ out) {
  __shared__ alignas(16) __bf16 As[BM * BK];
  __shared__ alignas(16) __bf16 Bs[BN * BK];
  f32x4 acc[4][4] = {};
  const int b = blockIdx.z;
  const int m0 = blockIdx.y * BM;
  const int n0 = blockIdx.x * BN;
  gemm_core(P + (size_t)b * SEQ * SEQ, SEQ,
            Vt + (size_t)b * DIM * SEQ, SEQ, SEQ, m0, n0, As, Bs, acc,
            MapId{}, MapId{});
  float* ob = out + (size_t)b * SEQ * DIM;
  const int t = threadIdx.x, w = t >> 6, lrow = t & 15, quad = (t >> 4) & 3;
  const int wm = (w >> 1) << 6, wn = (w & 1) << 6;
#pragma unroll
  for (int ni = 0; ni < 4; ++ni) {
    const int col = n0 + wn + ni * 16 + lrow;
#pragma unroll
    for (int mi = 0; mi < 4; ++mi) {
#pragma unroll
      for (int r = 0; r < 4; ++r) {
        const int row = m0 + wm + mi * 16 + quad * 4 + r;
        ob[(size_t)row * DIM + col] = acc[mi][ni][r];
      }
    }
  }
}

// ---------------------------------------------------------------------------
extern "C" void kernel_launch(void* const* d_in, const int* in_sizes, int n_in,
                              void* d_out, int out_size, void* d_ws, size_t ws_size,
                              hipStream_t stream) {
  const float* x  = (const float*)d_in[0];
  const float* Wq = (const float*)d_in[1];
  const float* bq = (const float*)d_in[2];
  const float* Wk = (const float*)d_in[3];
  const float* bk = (const float*)d_in[4];
  const float* Wv = (const float*)d_in[5];
  const float* bv = (const float*)d_in[6];
  float* out = (float*)d_out;  // reference output dtype is float32

  char* ws = (char*)d_ws;
  __bf16* Qp  = (__bf16*)(ws);                 // 32 MB
  __bf16* Kp  = (__bf16*)(ws + 33554432);      // 32 MB
  __bf16* Vt  = (__bf16*)(ws + 67108864);      // 16 MB
  float*  Sc  = (float*)(ws + 83886080);       // 64 MB [4][2048][2048] f32
  __bf16* P   = (__bf16*)(ws + 150994944);     // 32 MB [4][2048][2048] bf16
  // xp + W pairs alias the Sc region (dead once scores_kernel runs):
  __bf16* xp  = (__bf16*)(ws + 83886080);      // 32 MB
  __bf16* Wqp = (__bf16*)(ws + 117440512);     //  4 MB
  __bf16* Wkp = (__bf16*)(ws + 121634816);     //  4 MB
  __bf16* Wvp = (__bf16*)(ws + 125829120);     //  4 MB
  // peak 184,549,376 B

  dim3 blk(256, 1, 1);
  split_kernel<<<dim3(MTOT), blk, 0, stream>>>(x, xp);
  split_kernel<<<dim3(DIM), blk, 0, stream>>>(Wq, Wqp);
  split_kernel<<<dim3(DIM), blk, 0, stream>>>(Wk, Wkp);
  split_kernel<<<dim3(DIM), blk, 0, stream>>>(Wv, Wvp);
  qkv_kernel<<<dim3(DIM / BN, MTOT / BM, 3), blk, 0, stream>>>(
      xp, Wqp, bq, Wkp, bk, Wvp, bv, Qp, Kp, Vt);
  scores_kernel<<<dim3(SEQ / BN, SEQ / BM, NBATCH), blk, 0, stream>>>(Qp, Kp, Sc);
  softmax_kernel<<<dim3(MTOT), blk, 0, stream>>>(Sc, P);
  pv_kernel<<<dim3(DIM / BN, SEQ / BM, NBATCH), blk, 0, stream>>>(P, Vt, out);
}

// Round 9
// 327.680 us; speedup vs baseline: 2.5591x; 1.2901x over previous
//
#include <hip/hip_runtime.h>
#include <hip/hip_bf16.h>
#include <cstdint>
#include <cstddef>

// ---------------------------------------------------------------------------
// Self-attention, B=4 S=2048 D=1024. Inputs FLOAT32, output FLOAT32.
//   Q = x@Wq^T+bq ; K = x@Wk^T+bk ; V = x@Wv^T+bv
//   S = Q@K^T ; P = softmax(S)*(1/32) ; O = P@V
// Round-9: FP16 pipeline (was bf16). fp16 lo-terms are 8x smaller than bf16
// (2^-12 vs 2^-9), so cheaper compensation passes where bf16 failed (round 8
// measured the bf16 xhi@Wlo drop at 2.15e-3; fp16 analogs: /8).
//   * Q/K projections K=2048: [xhi|xlo] x [Whi|Whi] = x@Whi exactly
//     (drops x@Wlo -> ~2.7e-4 out-error).   V: K=1024 xhi@Whi (~3e-6).
//   * scores K=1024: Qh@Kh fp16 single planes (drops Q@Klo+Qlo@K -> ~3.1e-4).
//   * P, V in fp16: old bf16 P/V quantization baseline 4.9e-4 -> ~1e-4.
//   Predicted absmax ~4-7e-4 vs threshold 1.758e-3.
//   Keeps: XOR LDS swizzle (bank conflicts = 0), global_load_lds width 16,
//   fused split kernel, batched grids.
// Workspace (peak 150,994,944 B):
//   Qp [8192][1024] f16 @ 0        (16 MB)
//   Kp [8192][1024] f16 @ 16M      (16 MB)
//   Vt [4][1024][2048]  @ 32M      (16 MB)  V^T per batch, f16
//   Sc [4][2048][2048]  @ 48M      (64 MB)  f32 scores
//   P  [4][2048][2048]  @ 112M     (32 MB)  f16 probs
//   xp [8192][2048] f16 @ 48M      (32 MB)  aliases Sc (dead after qkv)
//   Wp 3x[1024][2048]   @ 80M      (12 MB)  aliases Sc (dead after qkv)
// ---------------------------------------------------------------------------

typedef __attribute__((ext_vector_type(8))) _Float16 f16x8;
typedef __attribute__((ext_vector_type(4))) _Float16 f16x4;
typedef __attribute__((ext_vector_type(4))) float f32x4;

#define BM 128
#define BN 128
#define BK 64

#define NBATCH 4
#define SEQ 2048
#define DIM 1024
#define MTOT (NBATCH * SEQ)   // 8192
#define PAIR (2 * DIM)        // 2048

__device__ __forceinline__ void async_ld16(const void* g, void* l) {
  __builtin_amdgcn_global_load_lds((__attribute__((address_space(1))) void*)(g),
                                   (__attribute__((address_space(3))) void*)(l),
                                   16, 0, 0);
}

struct MapId  { __device__ int operator()(int k) const { return k; } };
struct MapHiA { __device__ int operator()(int k) const { return k < DIM ? k : k - DIM; } };

// C[m0..+127][n0..+127] += A[m, mapa(k)] * B[n, mapb(k)]  (row-major, B^T GEMM)
// A,B f16; async global->LDS staging (XOR-swizzled slots); 4 waves 2x2;
// each wave 64x64 via 4x4 of 16x16x32 f16 MFMA.
template <typename MapA, typename MapB>
__device__ __forceinline__ void gemm_core(const _Float16* __restrict__ A, int lda,
                                          const _Float16* __restrict__ B, int ldb,
                                          int K, int m0, int n0,
                                          _Float16* As, _Float16* Bs,
                                          f32x4 (&acc)[4][4],
                                          MapA mapa, MapB mapb) {
  const int t = threadIdx.x;
  const int w = t >> 6;
  const int lrow = t & 15;
  const int quad = (t >> 4) & 3;
  const int wm = (w >> 1) << 6;
  const int wn = (w & 1) << 6;

  // Staging: thread t covers tile row rb (+32 per i), global colblock
  // (t&7)^(rb&7) (XOR swizzle; LDS dest is the wave-contiguous slot t&7).
  const int rb = t >> 3;                               // 0..31
  const int co = (((t & 7) ^ (rb & 7)) << 3);          // swizzled source col
  const size_t arow = (size_t)(m0 + rb) * lda + co;
  const size_t brow = (size_t)(n0 + rb) * ldb + co;

  const int sw = lrow & 7;  // row-phase for read-side swizzle

  for (int k0 = 0; k0 < K; k0 += BK) {
    const _Float16* Ap = A + arow + mapa(k0);
    const _Float16* Bp = B + brow + mapb(k0);
#pragma unroll
    for (int i = 0; i < 4; ++i)
      async_ld16(Ap + (size_t)(i * 32) * lda, As + i * 2048 + (w << 9));
#pragma unroll
    for (int i = 0; i < 4; ++i)
      async_ld16(Bp + (size_t)(i * 32) * ldb, Bs + i * 2048 + (w << 9));
    __syncthreads();
#pragma unroll
    for (int kk = 0; kk < BK; kk += 32) {
      const int slot = ((kk >> 3) + quad) ^ sw;  // swizzled 8-elt slot index
      f16x8 af[4], bfr[4];
#pragma unroll
      for (int mi = 0; mi < 4; ++mi)
        af[mi] = *(const f16x8*)(As + (wm + mi * 16 + lrow) * BK + (slot << 3));
#pragma unroll
      for (int ni = 0; ni < 4; ++ni)
        bfr[ni] = *(const f16x8*)(Bs + (wn + ni * 16 + lrow) * BK + (slot << 3));
#pragma unroll
      for (int mi = 0; mi < 4; ++mi)
#pragma unroll
        for (int ni = 0; ni < 4; ++ni)
          acc[mi][ni] = __builtin_amdgcn_mfma_f32_16x16x32_f16(af[mi], bfr[ni],
                                                              acc[mi][ni], 0, 0, 0);
    }
    __syncthreads();
  }
}

// ---------------------------------------------------------------------------
// Kernel 0: fused hi/lo split for x, Wq, Wk, Wv (flattened row index).
// f32 [R][1024] -> f16 [R][2048] as [hi | lo].
__global__ __launch_bounds__(256) void split_all_kernel(
    const float* __restrict__ x, const float* __restrict__ Wq,
    const float* __restrict__ Wk, const float* __restrict__ Wv,
    _Float16* __restrict__ xp, _Float16* __restrict__ Wqp,
    _Float16* __restrict__ Wkp, _Float16* __restrict__ Wvp) {
  int r = blockIdx.x;
  const float* src;
  _Float16* dst;
  if (r < MTOT)            { src = x;  dst = xp;  }
  else if (r < MTOT + DIM) { src = Wq; dst = Wqp; r -= MTOT; }
  else if (r < MTOT + 2 * DIM) { src = Wk; dst = Wkp; r -= MTOT + DIM; }
  else                     { src = Wv; dst = Wvp; r -= MTOT + 2 * DIM; }
  const int t = threadIdx.x;
  const float4 v = ((const float4*)(src + (size_t)r * DIM))[t];
  _Float16 h0 = (_Float16)v.x, h1 = (_Float16)v.y,
           h2 = (_Float16)v.z, h3 = (_Float16)v.w;
  f16x4 hi = {h0, h1, h2, h3};
  f16x4 lo = {(_Float16)(v.x - (float)h0), (_Float16)(v.y - (float)h1),
              (_Float16)(v.z - (float)h2), (_Float16)(v.w - (float)h3)};
  ((f16x4*)(dst + (size_t)r * PAIR))[t] = hi;
  ((f16x4*)(dst + (size_t)r * PAIR + DIM))[t] = lo;
}

// ---------------------------------------------------------------------------
// Kernel 1: QKV projections. z=0 Qp, z=1 Kp: K=2048, [xhi|xlo] x [Whi|Whi]
// (= x@Whi exactly). z=2 Vt: K=1024, xhi@Whi. Outputs single f16 planes.
__global__ __launch_bounds__(256, 2) void qkv_kernel(
    const _Float16* __restrict__ xp,
    const _Float16* __restrict__ Wqp, const float* __restrict__ bq,
    const _Float16* __restrict__ Wkp, const float* __restrict__ bk,
    const _Float16* __restrict__ Wvp, const float* __restrict__ bv,
    _Float16* __restrict__ Qp, _Float16* __restrict__ Kp,
    _Float16* __restrict__ Vt) {
  __shared__ alignas(16) _Float16 As[BM * BK];
  __shared__ alignas(16) _Float16 Bs[BN * BK];
  f32x4 acc[4][4] = {};
  const int z = blockIdx.z;
  const _Float16* W = (z == 0) ? Wqp : (z == 1) ? Wkp : Wvp;
  const float* bias = (z == 0) ? bq : (z == 1) ? bk : bv;
  const int m0 = blockIdx.y * BM;
  const int n0 = blockIdx.x * BN;
  const int Keff = (z == 2) ? DIM : PAIR;
  gemm_core(xp, PAIR, W, PAIR, Keff, m0, n0, As, Bs, acc, MapId{}, MapHiA{});

  const int t = threadIdx.x, w = t >> 6, lrow = t & 15, quad = (t >> 4) & 3;
  const int wm = (w >> 1) << 6, wn = (w & 1) << 6;
#pragma unroll
  for (int ni = 0; ni < 4; ++ni) {
    const int col = n0 + wn + ni * 16 + lrow;
    const float bb = bias[col];
#pragma unroll
    for (int mi = 0; mi < 4; ++mi) {
#pragma unroll
      for (int r = 0; r < 4; ++r) {
        const int row = m0 + wm + mi * 16 + quad * 4 + r;
        const float v = acc[mi][ni][r] + bb;
        if (z == 2) {
          // Vt[b][col][s]: b = row>>11, s = row&2047
          Vt[(size_t)(((row >> 11) << 10) + col) * SEQ + (row & (SEQ - 1))] =
              (_Float16)v;
        } else {
          _Float16* base = (z == 0) ? Qp : Kp;
          base[(size_t)row * DIM + col] = (_Float16)v;
        }
      }
    }
  }
}

// ---------------------------------------------------------------------------
// Kernel 2: scores[b] = Q[b] @ K[b]^T, f16 single planes (K=1024), f32 out.
__global__ __launch_bounds__(256, 2) void scores_kernel(
    const _Float16* __restrict__ Qp, const _Float16* __restrict__ Kp,
    float* __restrict__ Sc) {
  __shared__ alignas(16) _Float16 As[BM * BK];
  __shared__ alignas(16) _Float16 Bs[BN * BK];
  f32x4 acc[4][4] = {};
  const int b = blockIdx.z;
  const int m0 = blockIdx.y * BM;
  const int n0 = blockIdx.x * BN;
  gemm_core(Qp + (size_t)b * SEQ * DIM, DIM,
            Kp + (size_t)b * SEQ * DIM, DIM, DIM, m0, n0, As, Bs, acc,
            MapId{}, MapId{});
  float* out = Sc + (size_t)b * SEQ * SEQ;
  const int t = threadIdx.x, w = t >> 6, lrow = t & 15, quad = (t >> 4) & 3;
  const int wm = (w >> 1) << 6, wn = (w & 1) << 6;
#pragma unroll
  for (int ni = 0; ni < 4; ++ni) {
    const int col = n0 + wn + ni * 16 + lrow;
#pragma unroll
    for (int mi = 0; mi < 4; ++mi) {
#pragma unroll
      for (int r = 0; r < 4; ++r) {
        const int row = m0 + wm + mi * 16 + quad * 4 + r;
        out[(size_t)row * SEQ + col] = acc[mi][ni][r];
      }
    }
  }
}

// ---------------------------------------------------------------------------
// Kernel 3: row softmax over all batches, P = softmax(S)*(1/32), f16 out.
__global__ __launch_bounds__(256) void softmax_kernel(const float* __restrict__ Sc,
                                                      _Float16* __restrict__ P) {
  const int r = blockIdx.x;  // 0..8191 (batch-contiguous rows)
  const float* row = Sc + (size_t)r * SEQ;
  _Float16* prow = P + (size_t)r * SEQ;
  const int t = threadIdx.x;
  const int w = t >> 6;

  const float4 a = ((const float4*)row)[t];
  const float4 c = ((const float4*)row)[t + 256];

  float m = fmaxf(fmaxf(fmaxf(a.x, a.y), fmaxf(a.z, a.w)),
                  fmaxf(fmaxf(c.x, c.y), fmaxf(c.z, c.w)));
#pragma unroll
  for (int o = 32; o; o >>= 1) m = fmaxf(m, __shfl_down(m, o));
  __shared__ float red[8];
  if ((t & 63) == 0) red[w] = m;
  __syncthreads();
  m = fmaxf(fmaxf(red[0], red[1]), fmaxf(red[2], red[3]));

  float e[8];
  e[0] = __expf(a.x - m); e[1] = __expf(a.y - m);
  e[2] = __expf(a.z - m); e[3] = __expf(a.w - m);
  e[4] = __expf(c.x - m); e[5] = __expf(c.y - m);
  e[6] = __expf(c.z - m); e[7] = __expf(c.w - m);
  float s = ((e[0] + e[1]) + (e[2] + e[3])) + ((e[4] + e[5]) + (e[6] + e[7]));
#pragma unroll
  for (int o = 32; o; o >>= 1) s += __shfl_down(s, o);
  if ((t & 63) == 0) red[4 + w] = s;
  __syncthreads();
  s = (red[4] + red[5]) + (red[6] + red[7]);

  const float sc = 0.03125f / s;  // post-softmax 1/sqrt(Dk)=1/32 folded in
  f16x4 o1 = {(_Float16)(e[0] * sc), (_Float16)(e[1] * sc),
              (_Float16)(e[2] * sc), (_Float16)(e[3] * sc)};
  f16x4 o2 = {(_Float16)(e[4] * sc), (_Float16)(e[5] * sc),
              (_Float16)(e[6] * sc), (_Float16)(e[7] * sc)};
  ((f16x4*)prow)[t] = o1;
  ((f16x4*)prow)[t + 256] = o2;
}

// ---------------------------------------------------------------------------
// Kernel 4: O[b] = P[b] @ V[b]  (Vt [v][s] -> B^T GEMM, K=2048), f32 out.
__global__ __launch_bounds__(256, 2) void pv_kernel(
    const _Float16* __restrict__ P, const _Float16* __restrict__ Vt,
    float* __restrict__ out) {
  __shared__ alignas(16) _Float16 As[BM * BK];
  __shared__ alignas(16) _Float16 Bs[BN * BK];
  f32x4 acc[4][4] = {};
  const int b = blockIdx.z;
  const int m0 = blockIdx.y * BM;
  const int n0 = blockIdx.x * BN;
  gemm_core(P + (size_t)b * SEQ * SEQ, SEQ,
            Vt + (size_t)b * DIM * SEQ, SEQ, SEQ, m0, n0, As, Bs, acc,
            MapId{}, MapId{});
  float* ob = out + (size_t)b * SEQ * DIM;
  const int t = threadIdx.x, w = t >> 6, lrow = t & 15, quad = (t >> 4) & 3;
  const int wm = (w >> 1) << 6, wn = (w & 1) << 6;
#pragma unroll
  for (int ni = 0; ni < 4; ++ni) {
    const int col = n0 + wn + ni * 16 + lrow;
#pragma unroll
    for (int mi = 0; mi < 4; ++mi) {
#pragma unroll
      for (int r = 0; r < 4; ++r) {
        const int row = m0 + wm + mi * 16 + quad * 4 + r;
        ob[(size_t)row * DIM + col] = acc[mi][ni][r];
      }
    }
  }
}

// ---------------------------------------------------------------------------
extern "C" void kernel_launch(void* const* d_in, const int* in_sizes, int n_in,
                              void* d_out, int out_size, void* d_ws, size_t ws_size,
                              hipStream_t stream) {
  const float* x  = (const float*)d_in[0];
  const float* Wq = (const float*)d_in[1];
  const float* bq = (const float*)d_in[2];
  const float* Wk = (const float*)d_in[3];
  const float* bk = (const float*)d_in[4];
  const float* Wv = (const float*)d_in[5];
  const float* bv = (const float*)d_in[6];
  float* out = (float*)d_out;  // reference output dtype is float32

  char* ws = (char*)d_ws;
  _Float16* Qp  = (_Float16*)(ws);                 // 16 MB [8192][1024]
  _Float16* Kp  = (_Float16*)(ws + 16777216);      // 16 MB
  _Float16* Vt  = (_Float16*)(ws + 33554432);      // 16 MB [4][1024][2048]
  float*    Sc  = (float*)(ws + 50331648);         // 64 MB [4][2048][2048] f32
  _Float16* P   = (_Float16*)(ws + 117440512);     // 32 MB [4][2048][2048] f16
  // xp + W pairs alias the Sc region (dead once scores_kernel runs):
  _Float16* xp  = (_Float16*)(ws + 50331648);      // 32 MB [8192][2048]
  _Float16* Wqp = (_Float16*)(ws + 83886080);      //  4 MB
  _Float16* Wkp = (_Float16*)(ws + 88080384);      //  4 MB
  _Float16* Wvp = (_Float16*)(ws + 92274688);      //  4 MB
  // peak 150,994,944 B

  dim3 blk(256, 1, 1);
  split_all_kernel<<<dim3(MTOT + 3 * DIM), blk, 0, stream>>>(
      x, Wq, Wk, Wv, xp, Wqp, Wkp, Wvp);
  qkv_kernel<<<dim3(DIM / BN, MTOT / BM, 3), blk, 0, stream>>>(
      xp, Wqp, bq, Wkp, bk, Wvp, bv, Qp, Kp, Vt);
  scores_kernel<<<dim3(SEQ / BN, SEQ / BM, NBATCH), blk, 0, stream>>>(Qp, Kp, Sc);
  softmax_kernel<<<dim3(MTOT), blk, 0, stream>>>(Sc, P);
  pv_kernel<<<dim3(DIM / BN, SEQ / BM, NBATCH), blk, 0, stream>>>(P, Vt, out);
}

// Round 10
// 292.358 us; speedup vs baseline: 2.8683x; 1.1208x over previous
//
#include <hip/hip_runtime.h>
#include <hip/hip_bf16.h>
#include <cstdint>
#include <cstddef>

// ---------------------------------------------------------------------------
// Self-attention, B=4 S=2048 D=1024. Inputs FLOAT32, output FLOAT32.
//   Q = x@Wq^T+bq ; K = x@Wk^T+bk ; V = x@Wv^T+bv
//   S = Q@K^T ; P = softmax(S)*(1/32) ; O = P@V
// FP16 pipeline. Round-10 delta vs round 9 (327.7 us, absmax 4.88e-4):
//   * Q/K projections drop the xlo@Whi term: Q = xhi@Whi, K=1024 (was 2048).
//     Calibrated cost (round-8 measured bf16 term = 2.15e-3; fp16 = /8):
//     +2.7e-4 per term (Q,K) -> predicted absmax ~0.7-1.05e-3 < 1.758e-3.
//   * xlo / Wlo planes now dead -> split writes hi planes only.
//   * qkv all-z K=1024, uniform MapId, lda=1024.
//   Keeps: XOR LDS swizzle (conflicts=0), global_load_lds w16, batched grids.
// Error budget (calibrated): scores-drop 3.8e-4 + P/V f16 ~1e-4 (= measured
// 4.88e-4 baseline) + Q-drop 2.7e-4 + K-drop 2.7e-4.
// Workspace (peak 150,994,944 B):
//   Qp [8192][1024] f16 @ 0     (16 MB)
//   Kp [8192][1024] f16 @ 16M   (16 MB)
//   Vt [4][1024][2048]  @ 32M   (16 MB)  V^T per batch, f16
//   Sc [4][2048][2048]  @ 48M   (64 MB)  f32 scores
//   P  [4][2048][2048]  @ 112M  (32 MB)  f16 probs
//   xh [8192][1024] f16 @ 48M   (16 MB)  aliases Sc (dead after qkv)
//   Wh 3x[1024][1024]   @ 64M   ( 6 MB)  aliases Sc (dead after qkv)
// ---------------------------------------------------------------------------

typedef __attribute__((ext_vector_type(8))) _Float16 f16x8;
typedef __attribute__((ext_vector_type(4))) _Float16 f16x4;
typedef __attribute__((ext_vector_type(4))) float f32x4;

#define BM 128
#define BN 128
#define BK 64

#define NBATCH 4
#define SEQ 2048
#define DIM 1024
#define MTOT (NBATCH * SEQ)   // 8192

__device__ __forceinline__ void async_ld16(const void* g, void* l) {
  __builtin_amdgcn_global_load_lds((__attribute__((address_space(1))) void*)(g),
                                   (__attribute__((address_space(3))) void*)(l),
                                   16, 0, 0);
}

// C[m0..+127][n0..+127] += A[m,k] * B[n,k]  (row-major, B^T GEMM)
// A,B f16; async global->LDS staging (XOR-swizzled slots); 4 waves 2x2;
// each wave 64x64 via 4x4 of 16x16x32 f16 MFMA.
__device__ __forceinline__ void gemm_core(const _Float16* __restrict__ A, int lda,
                                          const _Float16* __restrict__ B, int ldb,
                                          int K, int m0, int n0,
                                          _Float16* As, _Float16* Bs,
                                          f32x4 (&acc)[4][4]) {
  const int t = threadIdx.x;
  const int w = t >> 6;
  const int lrow = t & 15;
  const int quad = (t >> 4) & 3;
  const int wm = (w >> 1) << 6;
  const int wn = (w & 1) << 6;

  // Staging: thread t covers tile row rb (+32 per i), global colblock
  // (t&7)^(rb&7) (XOR swizzle; LDS dest is the wave-contiguous slot t&7).
  const int rb = t >> 3;                               // 0..31
  const int co = (((t & 7) ^ (rb & 7)) << 3);          // swizzled source col
  const _Float16* Ap = A + (size_t)(m0 + rb) * lda + co;
  const _Float16* Bp = B + (size_t)(n0 + rb) * ldb + co;

  const int sw = lrow & 7;  // row-phase for read-side swizzle

  for (int k0 = 0; k0 < K; k0 += BK) {
#pragma unroll
    for (int i = 0; i < 4; ++i)
      async_ld16(Ap + (size_t)(i * 32) * lda + k0, As + i * 2048 + (w << 9));
#pragma unroll
    for (int i = 0; i < 4; ++i)
      async_ld16(Bp + (size_t)(i * 32) * ldb + k0, Bs + i * 2048 + (w << 9));
    __syncthreads();
#pragma unroll
    for (int kk = 0; kk < BK; kk += 32) {
      const int slot = ((kk >> 3) + quad) ^ sw;  // swizzled 8-elt slot index
      f16x8 af[4], bfr[4];
#pragma unroll
      for (int mi = 0; mi < 4; ++mi)
        af[mi] = *(const f16x8*)(As + (wm + mi * 16 + lrow) * BK + (slot << 3));
#pragma unroll
      for (int ni = 0; ni < 4; ++ni)
        bfr[ni] = *(const f16x8*)(Bs + (wn + ni * 16 + lrow) * BK + (slot << 3));
#pragma unroll
      for (int mi = 0; mi < 4; ++mi)
#pragma unroll
        for (int ni = 0; ni < 4; ++ni)
          acc[mi][ni] = __builtin_amdgcn_mfma_f32_16x16x32_f16(af[mi], bfr[ni],
                                                              acc[mi][ni], 0, 0, 0);
    }
    __syncthreads();
  }
}

// ---------------------------------------------------------------------------
// Kernel 0: fused f32 -> f16 (hi only) cast for x, Wq, Wk, Wv.
__global__ __launch_bounds__(256) void split_all_kernel(
    const float* __restrict__ x, const float* __restrict__ Wq,
    const float* __restrict__ Wk, const float* __restrict__ Wv,
    _Float16* __restrict__ xh, _Float16* __restrict__ Wqh,
    _Float16* __restrict__ Wkh, _Float16* __restrict__ Wvh) {
  int r = blockIdx.x;
  const float* src;
  _Float16* dst;
  if (r < MTOT)            { src = x;  dst = xh;  }
  else if (r < MTOT + DIM) { src = Wq; dst = Wqh; r -= MTOT; }
  else if (r < MTOT + 2 * DIM) { src = Wk; dst = Wkh; r -= MTOT + DIM; }
  else                     { src = Wv; dst = Wvh; r -= MTOT + 2 * DIM; }
  const int t = threadIdx.x;
  const float4 v = ((const float4*)(src + (size_t)r * DIM))[t];
  f16x4 hi = {(_Float16)v.x, (_Float16)v.y, (_Float16)v.z, (_Float16)v.w};
  ((f16x4*)(dst + (size_t)r * DIM))[t] = hi;
}

// ---------------------------------------------------------------------------
// Kernel 1: QKV projections, all K=1024 (xh @ Wh^T). z=0 Qp, z=1 Kp, z=2 Vt.
__global__ __launch_bounds__(256, 2) void qkv_kernel(
    const _Float16* __restrict__ xh,
    const _Float16* __restrict__ Wqh, const float* __restrict__ bq,
    const _Float16* __restrict__ Wkh, const float* __restrict__ bk,
    const _Float16* __restrict__ Wvh, const float* __restrict__ bv,
    _Float16* __restrict__ Qp, _Float16* __restrict__ Kp,
    _Float16* __restrict__ Vt) {
  __shared__ alignas(16) _Float16 As[BM * BK];
  __shared__ alignas(16) _Float16 Bs[BN * BK];
  f32x4 acc[4][4] = {};
  const int z = blockIdx.z;
  const _Float16* W = (z == 0) ? Wqh : (z == 1) ? Wkh : Wvh;
  const float* bias = (z == 0) ? bq : (z == 1) ? bk : bv;
  const int m0 = blockIdx.y * BM;
  const int n0 = blockIdx.x * BN;
  gemm_core(xh, DIM, W, DIM, DIM, m0, n0, As, Bs, acc);

  const int t = threadIdx.x, w = t >> 6, lrow = t & 15, quad = (t >> 4) & 3;
  const int wm = (w >> 1) << 6, wn = (w & 1) << 6;
#pragma unroll
  for (int ni = 0; ni < 4; ++ni) {
    const int col = n0 + wn + ni * 16 + lrow;
    const float bb = bias[col];
#pragma unroll
    for (int mi = 0; mi < 4; ++mi) {
#pragma unroll
      for (int r = 0; r < 4; ++r) {
        const int row = m0 + wm + mi * 16 + quad * 4 + r;
        const float v = acc[mi][ni][r] + bb;
        if (z == 2) {
          // Vt[b][col][s]: b = row>>11, s = row&2047
          Vt[(size_t)(((row >> 11) << 10) + col) * SEQ + (row & (SEQ - 1))] =
              (_Float16)v;
        } else {
          _Float16* base = (z == 0) ? Qp : Kp;
          base[(size_t)row * DIM + col] = (_Float16)v;
        }
      }
    }
  }
}

// ---------------------------------------------------------------------------
// Kernel 2: scores[b] = Q[b] @ K[b]^T (K=1024), f32 out. z=batch.
__global__ __launch_bounds__(256, 2) void scores_kernel(
    const _Float16* __restrict__ Qp, const _Float16* __restrict__ Kp,
    float* __restrict__ Sc) {
  __shared__ alignas(16) _Float16 As[BM * BK];
  __shared__ alignas(16) _Float16 Bs[BN * BK];
  f32x4 acc[4][4] = {};
  const int b = blockIdx.z;
  const int m0 = blockIdx.y * BM;
  const int n0 = blockIdx.x * BN;
  gemm_core(Qp + (size_t)b * SEQ * DIM, DIM,
            Kp + (size_t)b * SEQ * DIM, DIM, DIM, m0, n0, As, Bs, acc);
  float* out = Sc + (size_t)b * SEQ * SEQ;
  const int t = threadIdx.x, w = t >> 6, lrow = t & 15, quad = (t >> 4) & 3;
  const int wm = (w >> 1) << 6, wn = (w & 1) << 6;
#pragma unroll
  for (int ni = 0; ni < 4; ++ni) {
    const int col = n0 + wn + ni * 16 + lrow;
#pragma unroll
    for (int mi = 0; mi < 4; ++mi) {
#pragma unroll
      for (int r = 0; r < 4; ++r) {
        const int row = m0 + wm + mi * 16 + quad * 4 + r;
        out[(size_t)row * SEQ + col] = acc[mi][ni][r];
      }
    }
  }
}

// ---------------------------------------------------------------------------
// Kernel 3: row softmax over all batches, P = softmax(S)*(1/32), f16 out.
__global__ __launch_bounds__(256) void softmax_kernel(const float* __restrict__ Sc,
                                                      _Float16* __restrict__ P) {
  const int r = blockIdx.x;  // 0..8191 (batch-contiguous rows)
  const float* row = Sc + (size_t)r * SEQ;
  _Float16* prow = P + (size_t)r * SEQ;
  const int t = threadIdx.x;
  const int w = t >> 6;

  const float4 a = ((const float4*)row)[t];
  const float4 c = ((const float4*)row)[t + 256];

  float m = fmaxf(fmaxf(fmaxf(a.x, a.y), fmaxf(a.z, a.w)),
                  fmaxf(fmaxf(c.x, c.y), fmaxf(c.z, c.w)));
#pragma unroll
  for (int o = 32; o; o >>= 1) m = fmaxf(m, __shfl_down(m, o));
  __shared__ float red[8];
  if ((t & 63) == 0) red[w] = m;
  __syncthreads();
  m = fmaxf(fmaxf(red[0], red[1]), fmaxf(red[2], red[3]));

  float e[8];
  e[0] = __expf(a.x - m); e[1] = __expf(a.y - m);
  e[2] = __expf(a.z - m); e[3] = __expf(a.w - m);
  e[4] = __expf(c.x - m); e[5] = __expf(c.y - m);
  e[6] = __expf(c.z - m); e[7] = __expf(c.w - m);
  float s = ((e[0] + e[1]) + (e[2] + e[3])) + ((e[4] + e[5]) + (e[6] + e[7]));
#pragma unroll
  for (int o = 32; o; o >>= 1) s += __shfl_down(s, o);
  if ((t & 63) == 0) red[4 + w] = s;
  __syncthreads();
  s = (red[4] + red[5]) + (red[6] + red[7]);

  const float sc = 0.03125f / s;  // post-softmax 1/sqrt(Dk)=1/32 folded in
  f16x4 o1 = {(_Float16)(e[0] * sc), (_Float16)(e[1] * sc),
              (_Float16)(e[2] * sc), (_Float16)(e[3] * sc)};
  f16x4 o2 = {(_Float16)(e[4] * sc), (_Float16)(e[5] * sc),
              (_Float16)(e[6] * sc), (_Float16)(e[7] * sc)};
  ((f16x4*)prow)[t] = o1;
  ((f16x4*)prow)[t + 256] = o2;
}

// ---------------------------------------------------------------------------
// Kernel 4: O[b] = P[b] @ V[b]  (Vt [v][s] -> B^T GEMM, K=2048), f32 out.
__global__ __launch_bounds__(256, 2) void pv_kernel(
    const _Float16* __restrict__ P, const _Float16* __restrict__ Vt,
    float* __restrict__ out) {
  __shared__ alignas(16) _Float16 As[BM * BK];
  __shared__ alignas(16) _Float16 Bs[BN * BK];
  f32x4 acc[4][4] = {};
  const int b = blockIdx.z;
  const int m0 = blockIdx.y * BM;
  const int n0 = blockIdx.x * BN;
  gemm_core(P + (size_t)b * SEQ * SEQ, SEQ,
            Vt + (size_t)b * DIM * SEQ, SEQ, SEQ, m0, n0, As, Bs, acc);
  float* ob = out + (size_t)b * SEQ * DIM;
  const int t = threadIdx.x, w = t >> 6, lrow = t & 15, quad = (t >> 4) & 3;
  const int wm = (w >> 1) << 6, wn = (w & 1) << 6;
#pragma unroll
  for (int ni = 0; ni < 4; ++ni) {
    const int col = n0 + wn + ni * 16 + lrow;
#pragma unroll
    for (int mi = 0; mi < 4; ++mi) {
#pragma unroll
      for (int r = 0; r < 4; ++r) {
        const int row = m0 + wm + mi * 16 + quad * 4 + r;
        ob[(size_t)row * DIM + col] = acc[mi][ni][r];
      }
    }
  }
}

// ---------------------------------------------------------------------------
extern "C" void kernel_launch(void* const* d_in, const int* in_sizes, int n_in,
                              void* d_out, int out_size, void* d_ws, size_t ws_size,
                              hipStream_t stream) {
  const float* x  = (const float*)d_in[0];
  const float* Wq = (const float*)d_in[1];
  const float* bq = (const float*)d_in[2];
  const float* Wk = (const float*)d_in[3];
  const float* bk = (const float*)d_in[4];
  const float* Wv = (const float*)d_in[5];
  const float* bv = (const float*)d_in[6];
  float* out = (float*)d_out;  // reference output dtype is float32

  char* ws = (char*)d_ws;
  _Float16* Qp  = (_Float16*)(ws);                 // 16 MB [8192][1024]
  _Float16* Kp  = (_Float16*)(ws + 16777216);      // 16 MB
  _Float16* Vt  = (_Float16*)(ws + 33554432);      // 16 MB [4][1024][2048]
  float*    Sc  = (float*)(ws + 50331648);         // 64 MB [4][2048][2048] f32
  _Float16* P   = (_Float16*)(ws + 117440512);     // 32 MB [4][2048][2048] f16
  // xh + W hi planes alias the Sc region (dead once scores_kernel runs):
  _Float16* xh  = (_Float16*)(ws + 50331648);      // 16 MB [8192][1024]
  _Float16* Wqh = (_Float16*)(ws + 67108864);      //  2 MB
  _Float16* Wkh = (_Float16*)(ws + 69206016);      //  2 MB
  _Float16* Wvh = (_Float16*)(ws + 71303168);      //  2 MB
  // peak 150,994,944 B

  dim3 blk(256, 1, 1);
  split_all_kernel<<<dim3(MTOT + 3 * DIM), blk, 0, stream>>>(
      x, Wq, Wk, Wv, xh, Wqh, Wkh, Wvh);
  qkv_kernel<<<dim3(DIM / BN, MTOT / BM, 3), blk, 0, stream>>>(
      xh, Wqh, bq, Wkh, bk, Wvh, bv, Qp, Kp, Vt);
  scores_kernel<<<dim3(SEQ / BN, SEQ / BM, NBATCH), blk, 0, stream>>>(Qp, Kp, Sc);
  softmax_kernel<<<dim3(MTOT), blk, 0, stream>>>(Sc, P);
  pv_kernel<<<dim3(DIM / BN, SEQ / BM, NBATCH), blk, 0, stream>>>(P, Vt, out);
}

// Round 11
// 275.641 us; speedup vs baseline: 3.0422x; 1.0606x over previous
//
#include <hip/hip_runtime.h>
#include <hip/hip_bf16.h>
#include <cstdint>
#include <cstddef>

// ---------------------------------------------------------------------------
// Self-attention, B=4 S=2048 D=1024. Inputs FLOAT32, output FLOAT32.
//   Q = x@Wq^T+bq ; K = x@Wk^T+bk ; V = x@Wv^T+bv
//   S = Q@K^T ; P = softmax(S)*(1/32) ; O = P@V
// FP16 pipeline (calibrated: absmax 4.88e-4 vs threshold 1.758e-3).
// Round-11 deltas vs round 10 (292.4 us):
//   * Vt epilogue stores vectorized f16x4 (4 consecutive s per (mi,ni));
//     round-10 WRITE_SIZE was 81 MB vs 48 ideal from 2B scattered stores.
//   * softmax processes 2 rows/block (grid 4096): loads of both rows issue
//     together, shuffle reductions interleave, barriers amortized 2x
//     (was 3.8 TB/s effective, latency-bound).
//   Keeps: XOR LDS swizzle (conflicts=0), global_load_lds w16, K=1024
//   hi-plane GEMMs everywhere, batched grids.
// Workspace (peak 150,994,944 B):
//   Qp [8192][1024] f16 @ 0     (16 MB)
//   Kp [8192][1024] f16 @ 16M   (16 MB)
//   Vt [4][1024][2048]  @ 32M   (16 MB)  V^T per batch, f16
//   Sc [4][2048][2048]  @ 48M   (64 MB)  f32 scores
//   P  [4][2048][2048]  @ 112M  (32 MB)  f16 probs
//   xh [8192][1024] f16 @ 48M   (16 MB)  aliases Sc (dead after qkv)
//   Wh 3x[1024][1024]   @ 64M   ( 6 MB)  aliases Sc (dead after qkv)
// ---------------------------------------------------------------------------

typedef __attribute__((ext_vector_type(8))) _Float16 f16x8;
typedef __attribute__((ext_vector_type(4))) _Float16 f16x4;
typedef __attribute__((ext_vector_type(4))) float f32x4;

#define BM 128
#define BN 128
#define BK 64

#define NBATCH 4
#define SEQ 2048
#define DIM 1024
#define MTOT (NBATCH * SEQ)   // 8192

__device__ __forceinline__ void async_ld16(const void* g, void* l) {
  __builtin_amdgcn_global_load_lds((__attribute__((address_space(1))) void*)(g),
                                   (__attribute__((address_space(3))) void*)(l),
                                   16, 0, 0);
}

// C[m0..+127][n0..+127] += A[m,k] * B[n,k]  (row-major, B^T GEMM)
// A,B f16; async global->LDS staging (XOR-swizzled slots); 4 waves 2x2;
// each wave 64x64 via 4x4 of 16x16x32 f16 MFMA.
__device__ __forceinline__ void gemm_core(const _Float16* __restrict__ A, int lda,
                                          const _Float16* __restrict__ B, int ldb,
                                          int K, int m0, int n0,
                                          _Float16* As, _Float16* Bs,
                                          f32x4 (&acc)[4][4]) {
  const int t = threadIdx.x;
  const int w = t >> 6;
  const int lrow = t & 15;
  const int quad = (t >> 4) & 3;
  const int wm = (w >> 1) << 6;
  const int wn = (w & 1) << 6;

  // Staging: thread t covers tile row rb (+32 per i), global colblock
  // (t&7)^(rb&7) (XOR swizzle; LDS dest is the wave-contiguous slot t&7).
  const int rb = t >> 3;                               // 0..31
  const int co = (((t & 7) ^ (rb & 7)) << 3);          // swizzled source col
  const _Float16* Ap = A + (size_t)(m0 + rb) * lda + co;
  const _Float16* Bp = B + (size_t)(n0 + rb) * ldb + co;

  const int sw = lrow & 7;  // row-phase for read-side swizzle

  for (int k0 = 0; k0 < K; k0 += BK) {
#pragma unroll
    for (int i = 0; i < 4; ++i)
      async_ld16(Ap + (size_t)(i * 32) * lda + k0, As + i * 2048 + (w << 9));
#pragma unroll
    for (int i = 0; i < 4; ++i)
      async_ld16(Bp + (size_t)(i * 32) * ldb + k0, Bs + i * 2048 + (w << 9));
    __syncthreads();
#pragma unroll
    for (int kk = 0; kk < BK; kk += 32) {
      const int slot = ((kk >> 3) + quad) ^ sw;  // swizzled 8-elt slot index
      f16x8 af[4], bfr[4];
#pragma unroll
      for (int mi = 0; mi < 4; ++mi)
        af[mi] = *(const f16x8*)(As + (wm + mi * 16 + lrow) * BK + (slot << 3));
#pragma unroll
      for (int ni = 0; ni < 4; ++ni)
        bfr[ni] = *(const f16x8*)(Bs + (wn + ni * 16 + lrow) * BK + (slot << 3));
#pragma unroll
      for (int mi = 0; mi < 4; ++mi)
#pragma unroll
        for (int ni = 0; ni < 4; ++ni)
          acc[mi][ni] = __builtin_amdgcn_mfma_f32_16x16x32_f16(af[mi], bfr[ni],
                                                              acc[mi][ni], 0, 0, 0);
    }
    __syncthreads();
  }
}

// ---------------------------------------------------------------------------
// Kernel 0: fused f32 -> f16 cast for x, Wq, Wk, Wv.
__global__ __launch_bounds__(256) void split_all_kernel(
    const float* __restrict__ x, const float* __restrict__ Wq,
    const float* __restrict__ Wk, const float* __restrict__ Wv,
    _Float16* __restrict__ xh, _Float16* __restrict__ Wqh,
    _Float16* __restrict__ Wkh, _Float16* __restrict__ Wvh) {
  int r = blockIdx.x;
  const float* src;
  _Float16* dst;
  if (r < MTOT)            { src = x;  dst = xh;  }
  else if (r < MTOT + DIM) { src = Wq; dst = Wqh; r -= MTOT; }
  else if (r < MTOT + 2 * DIM) { src = Wk; dst = Wkh; r -= MTOT + DIM; }
  else                     { src = Wv; dst = Wvh; r -= MTOT + 2 * DIM; }
  const int t = threadIdx.x;
  const float4 v = ((const float4*)(src + (size_t)r * DIM))[t];
  f16x4 hi = {(_Float16)v.x, (_Float16)v.y, (_Float16)v.z, (_Float16)v.w};
  ((f16x4*)(dst + (size_t)r * DIM))[t] = hi;
}

// ---------------------------------------------------------------------------
// Kernel 1: QKV projections, all K=1024 (xh @ Wh^T). z=0 Qp, z=1 Kp, z=2 Vt.
__global__ __launch_bounds__(256, 2) void qkv_kernel(
    const _Float16* __restrict__ xh,
    const _Float16* __restrict__ Wqh, const float* __restrict__ bq,
    const _Float16* __restrict__ Wkh, const float* __restrict__ bk,
    const _Float16* __restrict__ Wvh, const float* __restrict__ bv,
    _Float16* __restrict__ Qp, _Float16* __restrict__ Kp,
    _Float16* __restrict__ Vt) {
  __shared__ alignas(16) _Float16 As[BM * BK];
  __shared__ alignas(16) _Float16 Bs[BN * BK];
  f32x4 acc[4][4] = {};
  const int z = blockIdx.z;
  const _Float16* W = (z == 0) ? Wqh : (z == 1) ? Wkh : Wvh;
  const float* bias = (z == 0) ? bq : (z == 1) ? bk : bv;
  const int m0 = blockIdx.y * BM;
  const int n0 = blockIdx.x * BN;
  gemm_core(xh, DIM, W, DIM, DIM, m0, n0, As, Bs, acc);

  const int t = threadIdx.x, w = t >> 6, lrow = t & 15, quad = (t >> 4) & 3;
  const int wm = (w >> 1) << 6, wn = (w & 1) << 6;
  if (z == 2) {
    // Vt[b][col][s]: 4 consecutive s per (mi,ni) -> vectorized f16x4 store.
    const int b = m0 >> 11;
    const int s_base = (m0 & (SEQ - 1)) + wm + quad * 4;
#pragma unroll
    for (int ni = 0; ni < 4; ++ni) {
      const int col = n0 + wn + ni * 16 + lrow;
      const float bb = bias[col];
      _Float16* vrow = Vt + (size_t)((b << 10) + col) * SEQ;
#pragma unroll
      for (int mi = 0; mi < 4; ++mi) {
        f16x4 v4 = {(_Float16)(acc[mi][ni][0] + bb),
                    (_Float16)(acc[mi][ni][1] + bb),
                    (_Float16)(acc[mi][ni][2] + bb),
                    (_Float16)(acc[mi][ni][3] + bb)};
        *(f16x4*)(vrow + s_base + mi * 16) = v4;
      }
    }
  } else {
    _Float16* base = (z == 0) ? Qp : Kp;
#pragma unroll
    for (int ni = 0; ni < 4; ++ni) {
      const int col = n0 + wn + ni * 16 + lrow;
      const float bb = bias[col];
#pragma unroll
      for (int mi = 0; mi < 4; ++mi) {
#pragma unroll
        for (int r = 0; r < 4; ++r) {
          const int row = m0 + wm + mi * 16 + quad * 4 + r;
          base[(size_t)row * DIM + col] = (_Float16)(acc[mi][ni][r] + bb);
        }
      }
    }
  }
}

// ---------------------------------------------------------------------------
// Kernel 2: scores[b] = Q[b] @ K[b]^T (K=1024), f32 out. z=batch.
__global__ __launch_bounds__(256, 2) void scores_kernel(
    const _Float16* __restrict__ Qp, const _Float16* __restrict__ Kp,
    float* __restrict__ Sc) {
  __shared__ alignas(16) _Float16 As[BM * BK];
  __shared__ alignas(16) _Float16 Bs[BN * BK];
  f32x4 acc[4][4] = {};
  const int b = blockIdx.z;
  const int m0 = blockIdx.y * BM;
  const int n0 = blockIdx.x * BN;
  gemm_core(Qp + (size_t)b * SEQ * DIM, DIM,
            Kp + (size_t)b * SEQ * DIM, DIM, DIM, m0, n0, As, Bs, acc);
  float* out = Sc + (size_t)b * SEQ * SEQ;
  const int t = threadIdx.x, w = t >> 6, lrow = t & 15, quad = (t >> 4) & 3;
  const int wm = (w >> 1) << 6, wn = (w & 1) << 6;
#pragma unroll
  for (int ni = 0; ni < 4; ++ni) {
    const int col = n0 + wn + ni * 16 + lrow;
#pragma unroll
    for (int mi = 0; mi < 4; ++mi) {
#pragma unroll
      for (int r = 0; r < 4; ++r) {
        const int row = m0 + wm + mi * 16 + quad * 4 + r;
        out[(size_t)row * SEQ + col] = acc[mi][ni][r];
      }
    }
  }
}

// ---------------------------------------------------------------------------
// Kernel 3: row softmax, 2 rows per block (ILP), P = softmax(S)*(1/32), f16.
__global__ __launch_bounds__(256) void softmax_kernel(const float* __restrict__ Sc,
                                                      _Float16* __restrict__ P) {
  const int r0 = blockIdx.x * 2;  // rows r0, r0+1
  const float* rowA = Sc + (size_t)r0 * SEQ;
  const float* rowB = rowA + SEQ;
  _Float16* prowA = P + (size_t)r0 * SEQ;
  _Float16* prowB = prowA + SEQ;
  const int t = threadIdx.x;
  const int w = t >> 6;

  const float4 a0 = ((const float4*)rowA)[t];
  const float4 a1 = ((const float4*)rowA)[t + 256];
  const float4 b0 = ((const float4*)rowB)[t];
  const float4 b1 = ((const float4*)rowB)[t + 256];

  float mA = fmaxf(fmaxf(fmaxf(a0.x, a0.y), fmaxf(a0.z, a0.w)),
                   fmaxf(fmaxf(a1.x, a1.y), fmaxf(a1.z, a1.w)));
  float mB = fmaxf(fmaxf(fmaxf(b0.x, b0.y), fmaxf(b0.z, b0.w)),
                   fmaxf(fmaxf(b1.x, b1.y), fmaxf(b1.z, b1.w)));
#pragma unroll
  for (int o = 32; o; o >>= 1) {
    mA = fmaxf(mA, __shfl_down(mA, o));
    mB = fmaxf(mB, __shfl_down(mB, o));
  }
  __shared__ float red[16];
  if ((t & 63) == 0) { red[w] = mA; red[w + 4] = mB; }
  __syncthreads();
  mA = fmaxf(fmaxf(red[0], red[1]), fmaxf(red[2], red[3]));
  mB = fmaxf(fmaxf(red[4], red[5]), fmaxf(red[6], red[7]));

  float eA[8], eB[8];
  eA[0] = __expf(a0.x - mA); eA[1] = __expf(a0.y - mA);
  eA[2] = __expf(a0.z - mA); eA[3] = __expf(a0.w - mA);
  eA[4] = __expf(a1.x - mA); eA[5] = __expf(a1.y - mA);
  eA[6] = __expf(a1.z - mA); eA[7] = __expf(a1.w - mA);
  eB[0] = __expf(b0.x - mB); eB[1] = __expf(b0.y - mB);
  eB[2] = __expf(b0.z - mB); eB[3] = __expf(b0.w - mB);
  eB[4] = __expf(b1.x - mB); eB[5] = __expf(b1.y - mB);
  eB[6] = __expf(b1.z - mB); eB[7] = __expf(b1.w - mB);
  float sA = ((eA[0] + eA[1]) + (eA[2] + eA[3])) + ((eA[4] + eA[5]) + (eA[6] + eA[7]));
  float sB = ((eB[0] + eB[1]) + (eB[2] + eB[3])) + ((eB[4] + eB[5]) + (eB[6] + eB[7]));
#pragma unroll
  for (int o = 32; o; o >>= 1) {
    sA += __shfl_down(sA, o);
    sB += __shfl_down(sB, o);
  }
  if ((t & 63) == 0) { red[8 + w] = sA; red[12 + w] = sB; }
  __syncthreads();
  sA = (red[8] + red[9]) + (red[10] + red[11]);
  sB = (red[12] + red[13]) + (red[14] + red[15]);

  const float scA = 0.03125f / sA;  // post-softmax 1/sqrt(Dk)=1/32 folded in
  const float scB = 0.03125f / sB;
  f16x4 oA0 = {(_Float16)(eA[0] * scA), (_Float16)(eA[1] * scA),
               (_Float16)(eA[2] * scA), (_Float16)(eA[3] * scA)};
  f16x4 oA1 = {(_Float16)(eA[4] * scA), (_Float16)(eA[5] * scA),
               (_Float16)(eA[6] * scA), (_Float16)(eA[7] * scA)};
  f16x4 oB0 = {(_Float16)(eB[0] * scB), (_Float16)(eB[1] * scB),
               (_Float16)(eB[2] * scB), (_Float16)(eB[3] * scB)};
  f16x4 oB1 = {(_Float16)(eB[4] * scB), (_Float16)(eB[5] * scB),
               (_Float16)(eB[6] * scB), (_Float16)(eB[7] * scB)};
  ((f16x4*)prowA)[t] = oA0;
  ((f16x4*)prowA)[t + 256] = oA1;
  ((f16x4*)prowB)[t] = oB0;
  ((f16x4*)prowB)[t + 256] = oB1;
}

// ---------------------------------------------------------------------------
// Kernel 4: O[b] = P[b] @ V[b]  (Vt [v][s] -> B^T GEMM, K=2048), f32 out.
__global__ __launch_bounds__(256, 2) void pv_kernel(
    const _Float16* __restrict__ P, const _Float16* __restrict__ Vt,
    float* __restrict__ out) {
  __shared__ alignas(16) _Float16 As[BM * BK];
  __shared__ alignas(16) _Float16 Bs[BN * BK];
  f32x4 acc[4][4] = {};
  const int b = blockIdx.z;
  const int m0 = blockIdx.y * BM;
  const int n0 = blockIdx.x * BN;
  gemm_core(P + (size_t)b * SEQ * SEQ, SEQ,
            Vt + (size_t)b * DIM * SEQ, SEQ, SEQ, m0, n0, As, Bs, acc);
  float* ob = out + (size_t)b * SEQ * DIM;
  const int t = threadIdx.x, w = t >> 6, lrow = t & 15, quad = (t >> 4) & 3;
  const int wm = (w >> 1) << 6, wn = (w & 1) << 6;
#pragma unroll
  for (int ni = 0; ni < 4; ++ni) {
    const int col = n0 + wn + ni * 16 + lrow;
#pragma unroll
    for (int mi = 0; mi < 4; ++mi) {
#pragma unroll
      for (int r = 0; r < 4; ++r) {
        const int row = m0 + wm + mi * 16 + quad * 4 + r;
        ob[(size_t)row * DIM + col] = acc[mi][ni][r];
      }
    }
  }
}

// ---------------------------------------------------------------------------
extern "C" void kernel_launch(void* const* d_in, const int* in_sizes, int n_in,
                              void* d_out, int out_size, void* d_ws, size_t ws_size,
                              hipStream_t stream) {
  const float* x  = (const float*)d_in[0];
  const float* Wq = (const float*)d_in[1];
  const float* bq = (const float*)d_in[2];
  const float* Wk = (const float*)d_in[3];
  const float* bk = (const float*)d_in[4];
  const float* Wv = (const float*)d_in[5];
  const float* bv = (const float*)d_in[6];
  float* out = (float*)d_out;  // reference output dtype is float32

  char* ws = (char*)d_ws;
  _Float16* Qp  = (_Float16*)(ws);                 // 16 MB [8192][1024]
  _Float16* Kp  = (_Float16*)(ws + 16777216);      // 16 MB
  _Float16* Vt  = (_Float16*)(ws + 33554432);      // 16 MB [4][1024][2048]
  float*    Sc  = (float*)(ws + 50331648);         // 64 MB [4][2048][2048] f32
  _Float16* P   = (_Float16*)(ws + 117440512);     // 32 MB [4][2048][2048] f16
  // xh + W hi planes alias the Sc region (dead once scores_kernel runs):
  _Float16* xh  = (_Float16*)(ws + 50331648);      // 16 MB [8192][1024]
  _Float16* Wqh = (_Float16*)(ws + 67108864);      //  2 MB
  _Float16* Wkh = (_Float16*)(ws + 69206016);      //  2 MB
  _Float16* Wvh = (_Float16*)(ws + 71303168);      //  2 MB
  // peak 150,994,944 B

  dim3 blk(256, 1, 1);
  split_all_kernel<<<dim3(MTOT + 3 * DIM), blk, 0, stream>>>(
      x, Wq, Wk, Wv, xh, Wqh, Wkh, Wvh);
  qkv_kernel<<<dim3(DIM / BN, MTOT / BM, 3), blk, 0, stream>>>(
      xh, Wqh, bq, Wkh, bk, Wvh, bv, Qp, Kp, Vt);
  scores_kernel<<<dim3(SEQ / BN, SEQ / BM, NBATCH), blk, 0, stream>>>(Qp, Kp, Sc);
  softmax_kernel<<<dim3(MTOT / 2), blk, 0, stream>>>(Sc, P);
  pv_kernel<<<dim3(DIM / BN, SEQ / BM, NBATCH), blk, 0, stream>>>(P, Vt, out);
}

// Round 12
// 240.155 us; speedup vs baseline: 3.4918x; 1.1478x over previous
//
#include <hip/hip_runtime.h>
#include <hip/hip_bf16.h>
#include <cstdint>
#include <cstddef>

// ---------------------------------------------------------------------------
// Self-attention, B=4 S=2048 D=1024. Inputs FLOAT32, output FLOAT32.
//   Q = x@Wq^T+bq ; K = x@Wk^T+bk ; V = x@Wv^T+bv
//   S = Q@K^T ; P = softmax(S)*(1/32) ; O = P@V
// FP16 pipeline (calibrated: absmax 4.88e-4 vs threshold 1.758e-3).
// Round-12 delta vs round 11 (275.6 us): XCD-aware block swizzle.
//   Round-11 qkv FETCH=182 MB vs ~22 MB unique input: grid x=n fastest +
//   round-robin block->XCD pinned each XCD to one n-column and streamed all
//   64 A-tiles (16 MB) through every XCD's 4 MB L2. Now 1-D grid decoded as
//   8m x 8n super-tiles: l mod 8 (XCD) = m-row, l>>3 = n -> each XCD holds
//   1 streaming A-tile + 8 resident B-tiles (2.25 MB < 4 MB L2); each A-tile
//   is fetched by exactly ONE XCD. Applied to qkv/scores/pv.
//   Keeps: XOR LDS swizzle (conflicts=0), global_load_lds w16, K=1024
//   hi-plane GEMMs, f16x4 Vt stores, 2-row softmax.
// Workspace (peak 150,994,944 B):
//   Qp [8192][1024] f16 @ 0     (16 MB)
//   Kp [8192][1024] f16 @ 16M   (16 MB)
//   Vt [4][1024][2048]  @ 32M   (16 MB)  V^T per batch, f16
//   Sc [4][2048][2048]  @ 48M   (64 MB)  f32 scores
//   P  [4][2048][2048]  @ 112M  (32 MB)  f16 probs
//   xh [8192][1024] f16 @ 48M   (16 MB)  aliases Sc (dead after qkv)
//   Wh 3x[1024][1024]   @ 64M   ( 6 MB)  aliases Sc (dead after qkv)
// ---------------------------------------------------------------------------

typedef __attribute__((ext_vector_type(8))) _Float16 f16x8;
typedef __attribute__((ext_vector_type(4))) _Float16 f16x4;
typedef __attribute__((ext_vector_type(4))) float f32x4;

#define BM 128
#define BN 128
#define BK 64

#define NBATCH 4
#define SEQ 2048
#define DIM 1024
#define MTOT (NBATCH * SEQ)   // 8192

__device__ __forceinline__ void async_ld16(const void* g, void* l) {
  __builtin_amdgcn_global_load_lds((__attribute__((address_space(1))) void*)(g),
                                   (__attribute__((address_space(3))) void*)(l),
                                   16, 0, 0);
}

// C[m0..+127][n0..+127] += A[m,k] * B[n,k]  (row-major, B^T GEMM)
// A,B f16; async global->LDS staging (XOR-swizzled slots); 4 waves 2x2;
// each wave 64x64 via 4x4 of 16x16x32 f16 MFMA.
__device__ __forceinline__ void gemm_core(const _Float16* __restrict__ A, int lda,
                                          const _Float16* __restrict__ B, int ldb,
                                          int K, int m0, int n0,
                                          _Float16* As, _Float16* Bs,
                                          f32x4 (&acc)[4][4]) {
  const int t = threadIdx.x;
  const int w = t >> 6;
  const int lrow = t & 15;
  const int quad = (t >> 4) & 3;
  const int wm = (w >> 1) << 6;
  const int wn = (w & 1) << 6;

  // Staging: thread t covers tile row rb (+32 per i), global colblock
  // (t&7)^(rb&7) (XOR swizzle; LDS dest is the wave-contiguous slot t&7).
  const int rb = t >> 3;                               // 0..31
  const int co = (((t & 7) ^ (rb & 7)) << 3);          // swizzled source col
  const _Float16* Ap = A + (size_t)(m0 + rb) * lda + co;
  const _Float16* Bp = B + (size_t)(n0 + rb) * ldb + co;

  const int sw = lrow & 7;  // row-phase for read-side swizzle

  for (int k0 = 0; k0 < K; k0 += BK) {
#pragma unroll
    for (int i = 0; i < 4; ++i)
      async_ld16(Ap + (size_t)(i * 32) * lda + k0, As + i * 2048 + (w << 9));
#pragma unroll
    for (int i = 0; i < 4; ++i)
      async_ld16(Bp + (size_t)(i * 32) * ldb + k0, Bs + i * 2048 + (w << 9));
    __syncthreads();
#pragma unroll
    for (int kk = 0; kk < BK; kk += 32) {
      const int slot = ((kk >> 3) + quad) ^ sw;  // swizzled 8-elt slot index
      f16x8 af[4], bfr[4];
#pragma unroll
      for (int mi = 0; mi < 4; ++mi)
        af[mi] = *(const f16x8*)(As + (wm + mi * 16 + lrow) * BK + (slot << 3));
#pragma unroll
      for (int ni = 0; ni < 4; ++ni)
        bfr[ni] = *(const f16x8*)(Bs + (wn + ni * 16 + lrow) * BK + (slot << 3));
#pragma unroll
      for (int mi = 0; mi < 4; ++mi)
#pragma unroll
        for (int ni = 0; ni < 4; ++ni)
          acc[mi][ni] = __builtin_amdgcn_mfma_f32_16x16x32_f16(af[mi], bfr[ni],
                                                              acc[mi][ni], 0, 0, 0);
    }
    __syncthreads();
  }
}

// ---------------------------------------------------------------------------
// Kernel 0: fused f32 -> f16 cast for x, Wq, Wk, Wv.
__global__ __launch_bounds__(256) void split_all_kernel(
    const float* __restrict__ x, const float* __restrict__ Wq,
    const float* __restrict__ Wk, const float* __restrict__ Wv,
    _Float16* __restrict__ xh, _Float16* __restrict__ Wqh,
    _Float16* __restrict__ Wkh, _Float16* __restrict__ Wvh) {
  int r = blockIdx.x;
  const float* src;
  _Float16* dst;
  if (r < MTOT)            { src = x;  dst = xh;  }
  else if (r < MTOT + DIM) { src = Wq; dst = Wqh; r -= MTOT; }
  else if (r < MTOT + 2 * DIM) { src = Wk; dst = Wkh; r -= MTOT + DIM; }
  else                     { src = Wv; dst = Wvh; r -= MTOT + 2 * DIM; }
  const int t = threadIdx.x;
  const float4 v = ((const float4*)(src + (size_t)r * DIM))[t];
  f16x4 hi = {(_Float16)v.x, (_Float16)v.y, (_Float16)v.z, (_Float16)v.w};
  ((f16x4*)(dst + (size_t)r * DIM))[t] = hi;
}

// ---------------------------------------------------------------------------
// Kernel 1: QKV projections, all K=1024 (xh @ Wh^T). 1-D grid, 512 blocks/z.
// Decode: z = l>>9; within z: m = (l&7) + 8*(l>>6), n = (l>>3)&7  (8x8
// super-tiles; XCD = l&7 handles one m-row, B-tiles L2-resident).
__global__ __launch_bounds__(256, 2) void qkv_kernel(
    const _Float16* __restrict__ xh,
    const _Float16* __restrict__ Wqh, const float* __restrict__ bq,
    const _Float16* __restrict__ Wkh, const float* __restrict__ bk,
    const _Float16* __restrict__ Wvh, const float* __restrict__ bv,
    _Float16* __restrict__ Qp, _Float16* __restrict__ Kp,
    _Float16* __restrict__ Vt) {
  __shared__ alignas(16) _Float16 As[BM * BK];
  __shared__ alignas(16) _Float16 Bs[BN * BK];
  f32x4 acc[4][4] = {};
  const int l = blockIdx.x;
  const int z = l >> 9;
  const int r9 = l & 511;
  const int m0 = (((r9 & 7) | ((r9 >> 6) << 3))) * BM;
  const int n0 = ((r9 >> 3) & 7) * BN;
  const _Float16* W = (z == 0) ? Wqh : (z == 1) ? Wkh : Wvh;
  const float* bias = (z == 0) ? bq : (z == 1) ? bk : bv;
  gemm_core(xh, DIM, W, DIM, DIM, m0, n0, As, Bs, acc);

  const int t = threadIdx.x, w = t >> 6, lrow = t & 15, quad = (t >> 4) & 3;
  const int wm = (w >> 1) << 6, wn = (w & 1) << 6;
  if (z == 2) {
    // Vt[b][col][s]: 4 consecutive s per (mi,ni) -> vectorized f16x4 store.
    const int b = m0 >> 11;
    const int s_base = (m0 & (SEQ - 1)) + wm + quad * 4;
#pragma unroll
    for (int ni = 0; ni < 4; ++ni) {
      const int col = n0 + wn + ni * 16 + lrow;
      const float bb = bias[col];
      _Float16* vrow = Vt + (size_t)((b << 10) + col) * SEQ;
#pragma unroll
      for (int mi = 0; mi < 4; ++mi) {
        f16x4 v4 = {(_Float16)(acc[mi][ni][0] + bb),
                    (_Float16)(acc[mi][ni][1] + bb),
                    (_Float16)(acc[mi][ni][2] + bb),
                    (_Float16)(acc[mi][ni][3] + bb)};
        *(f16x4*)(vrow + s_base + mi * 16) = v4;
      }
    }
  } else {
    _Float16* base = (z == 0) ? Qp : Kp;
#pragma unroll
    for (int ni = 0; ni < 4; ++ni) {
      const int col = n0 + wn + ni * 16 + lrow;
      const float bb = bias[col];
#pragma unroll
      for (int mi = 0; mi < 4; ++mi) {
#pragma unroll
        for (int r = 0; r < 4; ++r) {
          const int row = m0 + wm + mi * 16 + quad * 4 + r;
          base[(size_t)row * DIM + col] = (_Float16)(acc[mi][ni][r] + bb);
        }
      }
    }
  }
}

// ---------------------------------------------------------------------------
// Kernel 2: scores[b] = Q[b] @ K[b]^T (K=1024), f32 out. 1-D grid,
// 256 blocks/batch: s=r>>6 picks (m_sup=s&1, n_sup=s>>1); m=(r&7)+8*m_sup,
// n=((r>>3)&7)+8*n_sup.
__global__ __launch_bounds__(256, 2) void scores_kernel(
    const _Float16* __restrict__ Qp, const _Float16* __restrict__ Kp,
    float* __restrict__ Sc) {
  __shared__ alignas(16) _Float16 As[BM * BK];
  __shared__ alignas(16) _Float16 Bs[BN * BK];
  f32x4 acc[4][4] = {};
  const int l = blockIdx.x;
  const int b = l >> 8;
  const int r8 = l & 255;
  const int s = r8 >> 6;
  const int m0 = ((r8 & 7) | ((s & 1) << 3)) * BM;
  const int n0 = (((r8 >> 3) & 7) | ((s >> 1) << 3)) * BN;
  gemm_core(Qp + (size_t)b * SEQ * DIM, DIM,
            Kp + (size_t)b * SEQ * DIM, DIM, DIM, m0, n0, As, Bs, acc);
  float* out = Sc + (size_t)b * SEQ * SEQ;
  const int t = threadIdx.x, w = t >> 6, lrow = t & 15, quad = (t >> 4) & 3;
  const int wm = (w >> 1) << 6, wn = (w & 1) << 6;
#pragma unroll
  for (int ni = 0; ni < 4; ++ni) {
    const int col = n0 + wn + ni * 16 + lrow;
#pragma unroll
    for (int mi = 0; mi < 4; ++mi) {
#pragma unroll
      for (int r = 0; r < 4; ++r) {
        const int row = m0 + wm + mi * 16 + quad * 4 + r;
        out[(size_t)row * SEQ + col] = acc[mi][ni][r];
      }
    }
  }
}

// ---------------------------------------------------------------------------
// Kernel 3: row softmax, 2 rows per block (ILP), P = softmax(S)*(1/32), f16.
__global__ __launch_bounds__(256) void softmax_kernel(const float* __restrict__ Sc,
                                                      _Float16* __restrict__ P) {
  const int r0 = blockIdx.x * 2;  // rows r0, r0+1
  const float* rowA = Sc + (size_t)r0 * SEQ;
  const float* rowB = rowA + SEQ;
  _Float16* prowA = P + (size_t)r0 * SEQ;
  _Float16* prowB = prowA + SEQ;
  const int t = threadIdx.x;
  const int w = t >> 6;

  const float4 a0 = ((const float4*)rowA)[t];
  const float4 a1 = ((const float4*)rowA)[t + 256];
  const float4 b0 = ((const float4*)rowB)[t];
  const float4 b1 = ((const float4*)rowB)[t + 256];

  float mA = fmaxf(fmaxf(fmaxf(a0.x, a0.y), fmaxf(a0.z, a0.w)),
                   fmaxf(fmaxf(a1.x, a1.y), fmaxf(a1.z, a1.w)));
  float mB = fmaxf(fmaxf(fmaxf(b0.x, b0.y), fmaxf(b0.z, b0.w)),
                   fmaxf(fmaxf(b1.x, b1.y), fmaxf(b1.z, b1.w)));
#pragma unroll
  for (int o = 32; o; o >>= 1) {
    mA = fmaxf(mA, __shfl_down(mA, o));
    mB = fmaxf(mB, __shfl_down(mB, o));
  }
  __shared__ float red[16];
  if ((t & 63) == 0) { red[w] = mA; red[w + 4] = mB; }
  __syncthreads();
  mA = fmaxf(fmaxf(red[0], red[1]), fmaxf(red[2], red[3]));
  mB = fmaxf(fmaxf(red[4], red[5]), fmaxf(red[6], red[7]));

  float eA[8], eB[8];
  eA[0] = __expf(a0.x - mA); eA[1] = __expf(a0.y - mA);
  eA[2] = __expf(a0.z - mA); eA[3] = __expf(a0.w - mA);
  eA[4] = __expf(a1.x - mA); eA[5] = __expf(a1.y - mA);
  eA[6] = __expf(a1.z - mA); eA[7] = __expf(a1.w - mA);
  eB[0] = __expf(b0.x - mB); eB[1] = __expf(b0.y - mB);
  eB[2] = __expf(b0.z - mB); eB[3] = __expf(b0.w - mB);
  eB[4] = __expf(b1.x - mB); eB[5] = __expf(b1.y - mB);
  eB[6] = __expf(b1.z - mB); eB[7] = __expf(b1.w - mB);
  float sA = ((eA[0] + eA[1]) + (eA[2] + eA[3])) + ((eA[4] + eA[5]) + (eA[6] + eA[7]));
  float sB = ((eB[0] + eB[1]) + (eB[2] + eB[3])) + ((eB[4] + eB[5]) + (eB[6] + eB[7]));
#pragma unroll
  for (int o = 32; o; o >>= 1) {
    sA += __shfl_down(sA, o);
    sB += __shfl_down(sB, o);
  }
  if ((t & 63) == 0) { red[8 + w] = sA; red[12 + w] = sB; }
  __syncthreads();
  sA = (red[8] + red[9]) + (red[10] + red[11]);
  sB = (red[12] + red[13]) + (red[14] + red[15]);

  const float scA = 0.03125f / sA;  // post-softmax 1/sqrt(Dk)=1/32 folded in
  const float scB = 0.03125f / sB;
  f16x4 oA0 = {(_Float16)(eA[0] * scA), (_Float16)(eA[1] * scA),
               (_Float16)(eA[2] * scA), (_Float16)(eA[3] * scA)};
  f16x4 oA1 = {(_Float16)(eA[4] * scA), (_Float16)(eA[5] * scA),
               (_Float16)(eA[6] * scA), (_Float16)(eA[7] * scA)};
  f16x4 oB0 = {(_Float16)(eB[0] * scB), (_Float16)(eB[1] * scB),
               (_Float16)(eB[2] * scB), (_Float16)(eB[3] * scB)};
  f16x4 oB1 = {(_Float16)(eB[4] * scB), (_Float16)(eB[5] * scB),
               (_Float16)(eB[6] * scB), (_Float16)(eB[7] * scB)};
  ((f16x4*)prowA)[t] = oA0;
  ((f16x4*)prowA)[t + 256] = oA1;
  ((f16x4*)prowB)[t] = oB0;
  ((f16x4*)prowB)[t + 256] = oB1;
}

// ---------------------------------------------------------------------------
// Kernel 4: O[b] = P[b] @ V[b]  (Vt [v][s] -> B^T GEMM, K=2048), f32 out.
// 1-D grid, 128 blocks/batch: m=(r&7)+8*(r>>6), n=(r>>3)&7.
__global__ __launch_bounds__(256, 2) void pv_kernel(
    const _Float16* __restrict__ P, const _Float16* __restrict__ Vt,
    float* __restrict__ out) {
  __shared__ alignas(16) _Float16 As[BM * BK];
  __shared__ alignas(16) _Float16 Bs[BN * BK];
  f32x4 acc[4][4] = {};
  const int l = blockIdx.x;
  const int b = l >> 7;
  const int r7 = l & 127;
  const int m0 = ((r7 & 7) | ((r7 >> 6) << 3)) * BM;
  const int n0 = ((r7 >> 3) & 7) * BN;
  gemm_core(P + (size_t)b * SEQ * SEQ, SEQ,
            Vt + (size_t)b * DIM * SEQ, SEQ, SEQ, m0, n0, As, Bs, acc);
  float* ob = out + (size_t)b * SEQ * DIM;
  const int t = threadIdx.x, w = t >> 6, lrow = t & 15, quad = (t >> 4) & 3;
  const int wm = (w >> 1) << 6, wn = (w & 1) << 6;
#pragma unroll
  for (int ni = 0; ni < 4; ++ni) {
    const int col = n0 + wn + ni * 16 + lrow;
#pragma unroll
    for (int mi = 0; mi < 4; ++mi) {
#pragma unroll
      for (int r = 0; r < 4; ++r) {
        const int row = m0 + wm + mi * 16 + quad * 4 + r;
        ob[(size_t)row * DIM + col] = acc[mi][ni][r];
      }
    }
  }
}

// ---------------------------------------------------------------------------
extern "C" void kernel_launch(void* const* d_in, const int* in_sizes, int n_in,
                              void* d_out, int out_size, void* d_ws, size_t ws_size,
                              hipStream_t stream) {
  const float* x  = (const float*)d_in[0];
  const float* Wq = (const float*)d_in[1];
  const float* bq = (const float*)d_in[2];
  const float* Wk = (const float*)d_in[3];
  const float* bk = (const float*)d_in[4];
  const float* Wv = (const float*)d_in[5];
  const float* bv = (const float*)d_in[6];
  float* out = (float*)d_out;  // reference output dtype is float32

  char* ws = (char*)d_ws;
  _Float16* Qp  = (_Float16*)(ws);                 // 16 MB [8192][1024]
  _Float16* Kp  = (_Float16*)(ws + 16777216);      // 16 MB
  _Float16* Vt  = (_Float16*)(ws + 33554432);      // 16 MB [4][1024][2048]
  float*    Sc  = (float*)(ws + 50331648);         // 64 MB [4][2048][2048] f32
  _Float16* P   = (_Float16*)(ws + 117440512);     // 32 MB [4][2048][2048] f16
  // xh + W hi planes alias the Sc region (dead once scores_kernel runs):
  _Float16* xh  = (_Float16*)(ws + 50331648);      // 16 MB [8192][1024]
  _Float16* Wqh = (_Float16*)(ws + 67108864);      //  2 MB
  _Float16* Wkh = (_Float16*)(ws + 69206016);      //  2 MB
  _Float16* Wvh = (_Float16*)(ws + 71303168);      //  2 MB
  // peak 150,994,944 B

  dim3 blk(256, 1, 1);
  split_all_kernel<<<dim3(MTOT + 3 * DIM), blk, 0, stream>>>(
      x, Wq, Wk, Wv, xh, Wqh, Wkh, Wvh);
  qkv_kernel<<<dim3(3 * 512), blk, 0, stream>>>(
      xh, Wqh, bq, Wkh, bk, Wvh, bv, Qp, Kp, Vt);
  scores_kernel<<<dim3(NBATCH * 256), blk, 0, stream>>>(Qp, Kp, Sc);
  softmax_kernel<<<dim3(MTOT / 2), blk, 0, stream>>>(Sc, P);
  pv_kernel<<<dim3(NBATCH * 128), blk, 0, stream>>>(P, Vt, out);
}